// Round 9
// baseline (975.477 us; speedup 1.0000x reference)
//
#include <hip/hip_runtime.h>
#include <math.h>

#define T_SAMPLES 96000
#define NFRAMES 801
#define NBINS 513
#define FROWS 515   // NBINS + 2 guard rows (index f+1; rows 0 and 514 are zero)
#define EPS32 1.1920928955078125e-07f

typedef _Float16 f16;
typedef f16 f16x2 __attribute__((ext_vector_type(2)));
typedef f16 f16x4 __attribute__((ext_vector_type(4)));
typedef f16 f16x8 __attribute__((ext_vector_type(8)));
typedef float f32x4 __attribute__((ext_vector_type(4)));
typedef float f32x16 __attribute__((ext_vector_type(16)));

// ---------------------------------------------------------------- STFT ----
__global__ __launch_bounds__(512) void stft_kernel(const float* __restrict__ y,
                                                   float* __restrict__ mag)
{
    int t = blockIdx.x;   // frame 0..800
    int b = blockIdx.y;   // batch 0..3
    int tid = threadIdx.x;

    __shared__ float2 buf[2][1024];

    const float* yb = y + (size_t)b * T_SAMPLES;
    for (int n = tid; n < 1024; n += 512) {
        int j = t * 120 + n - 512;          // reflect pad 512 both sides
        if (j < 0) j = -j;
        if (j >= T_SAMPLES) j = 2 * T_SAMPLES - 2 - j;
        float v = yb[j];
        int np_ = n - 212;                  // window placed at lp=212, len 600
        float w = 0.0f;
        if (np_ >= 0 && np_ < 600)
            w = 0.5f * (1.0f - cospif((float)np_ * (1.0f / 300.0f)));
        buf[0][n] = make_float2(v * w, 0.0f);
    }
    __syncthreads();

    int srcb = 0;
    #pragma unroll
    for (int stage = 0; stage < 10; ++stage) {
        int m  = 1 << stage;
        int jm = (tid >> stage) << stage;   // j*m
        float jf = (float)jm * (1.0f / 512.0f);
        float wr = cospif(jf);
        float wi = -sinpif(jf);             // e^{-i pi j/l}
        float2 a  = buf[srcb][tid];
        float2 bb = buf[srcb][tid + 512];
        float2 s  = make_float2(a.x + bb.x, a.y + bb.y);
        float2 d  = make_float2(a.x - bb.x, a.y - bb.y);
        float2 dw = make_float2(d.x * wr - d.y * wi, d.x * wi + d.y * wr);
        buf[srcb ^ 1][tid + jm]     = s;
        buf[srcb ^ 1][tid + jm + m] = dw;
        __syncthreads();
        srcb ^= 1;
    }

    float2 v = buf[srcb][tid];
    float msq = v.x * v.x + v.y * v.y;
    mag[((size_t)b * NBINS + tid) * NFRAMES + t] = sqrtf(fmaxf(msq, EPS32));
    if (tid == 0) {
        float2 v5 = buf[srcb][512];
        float m5 = v5.x * v5.x + v5.y * v5.y;
        mag[((size_t)b * NBINS + 512) * NFRAMES + t] = sqrtf(fmaxf(m5, EPS32));
    }
}

// ----------------------------------------------------------- zero pads ----
// Zeroes guard rows (0, 514 per b) and right-tail columns of each fp16
// activation copy, every call (ws is poisoned once before timing).
__global__ __launch_bounds__(256) void zero_pads(f16* p0, f16* p1, f16* p2, f16* p3)
{
    const int TPs[4]   = {840, 456, 264, 136};
    const int tails[4] = {840, 420, 228, 133};   // L0 tail covered by harmonic
    f16* ptrs[4] = {p0, p1, p2, p3};
    int l = blockIdx.y;
    f16* p = ptrs[l];
    int TP = TPs[l], tail = tails[l];
    int rowSlots   = TP * 4;                      // 16B slots per row
    int guardSlots = 8 * rowSlots;                // 4b x {0,514}
    int tailCols   = TP - tail;
    int tailSlots  = 4 * FROWS * tailCols * 4;
    int total = guardSlots + tailSlots;
    f16x8 z;
    #pragma unroll
    for (int j = 0; j < 8; ++j) z[j] = (f16)0.f;
    for (int i = blockIdx.x * 256 + threadIdx.x; i < total; i += gridDim.x * 256) {
        size_t slot;
        if (i < guardSlots) {
            int rs = i / rowSlots;
            int q  = i - rs * rowSlots;
            int b  = rs >> 1;
            int r  = (rs & 1) ? (FROWS - 1) : 0;
            slot = ((size_t)(b * FROWS + r)) * rowSlots + q;
        } else {
            int j2 = i - guardSlots;
            int per = tailCols * 4;
            int row = j2 / per;
            int q   = j2 - row * per;
            slot = ((size_t)row * TP + tail) * 4 + q;
        }
        *reinterpret_cast<f16x8*>((char*)p + slot * 16) = z;
    }
}

// -------------------------------------------------- fused weight prep ----
__global__ __launch_bounds__(256) void prep_kernel(
    const float* __restrict__ v0, const float* __restrict__ g0,
    const float* __restrict__ v1, const float* __restrict__ g1,
    const float* __restrict__ v2, const float* __restrict__ g2,
    const float* __restrict__ v3, const float* __restrict__ g3,
    const float* __restrict__ v4, const float* __restrict__ g4,
    const float* __restrict__ vo, const float* __restrict__ go,
    float* __restrict__ w0n, float* __restrict__ won,
    f16* __restrict__ A1, f16* __restrict__ A2,
    f16* __restrict__ A3, f16* __restrict__ A4)
{
    int blk = blockIdx.x;
    int tid = threadIdx.x;

    const float *v, *g; f16* Ap = nullptr; float* outf = nullptr;
    int o, per_o, KW = 9;
    if (blk < 32)        { v = v1; g = g1; Ap = A1; o = blk;       per_o = 864; }
    else if (blk < 64)   { v = v2; g = g2; Ap = A2; o = blk - 32;  per_o = 864; }
    else if (blk < 96)   { v = v3; g = g3; Ap = A3; o = blk - 64;  per_o = 864; }
    else if (blk < 128)  { v = v4; g = g4; Ap = A4; o = blk - 96;  per_o = 288; KW = 3; }
    else if (blk < 160)  { v = v0; g = g0; outf = w0n; o = blk - 128; per_o = 49; }
    else                 { v = vo; g = go; outf = won; o = 0;        per_o = 288; }

    const float* vv = v + (size_t)o * per_o;
    __shared__ float red[256];
    float s = 0.f;
    for (int i = tid; i < per_o; i += 256) { float x = vv[i]; s = fmaf(x, x, s); }
    red[tid] = s;
    __syncthreads();
    for (int k = 128; k > 0; k >>= 1) {
        if (tid < k) red[tid] += red[tid + k];
        __syncthreads();
    }
    float scale = g[o] / sqrtf(red[0]);

    if (outf) {
        for (int i = tid; i < per_o; i += 256)
            outf[(size_t)o * per_o + i] = vv[i] * scale;
    } else {
        for (int i = tid; i < per_o; i += 256) {
            int tap = i >> 5;
            int c   = i & 31;
            int df  = tap / KW, kw = tap - df * KW;
            float val = vv[(c * 3 + df) * KW + kw] * scale;
            int l = ((c >> 3) & 1) * 32 + o;
            int ch = c >> 4;
            int j = c & 7;
            Ap[(((tap * 2 + ch) * 64 + l) << 3) + j] = (f16)val;
        }
    }
}

// -------------------------------------------------------- harmonic conv ----
// Writes fp32 fmap0 + padded swizzle-baked fp16 copy f0c [b][f+1][tg=t+4][32c]
// (TP0=840; zeros for tg in [805,840); left pad [0,4); guard rows by zero_pads).
__global__ __launch_bounds__(256) void harmonic_kernel(const float* __restrict__ mag,
                                                       const float* __restrict__ wn,
                                                       const float* __restrict__ bias,
                                                       float* __restrict__ out,
                                                       f16* __restrict__ f0c,
                                                       float fr4, float fr5)
{
    int f = blockIdx.x;
    int b = blockIdx.y;
    int tid = threadIdx.x;

    __shared__ float rows[3][808];

    const float* mb = mag + (size_t)b * NBINS * NFRAMES;

    for (int i = tid; i < 808; i += 256) {
        int tt = i - 3;
        bool ok = (tt >= 0) && (tt < NFRAMES);
        float m336 = (ok && f >= 336) ? mb[(size_t)(f - 336) * NFRAMES + tt] : 0.f;
        float m337 = (ok && f >= 337) ? mb[(size_t)(f - 337) * NFRAMES + tt] : 0.f;
        float m154 = (ok && f >= 154) ? mb[(size_t)(f - 154) * NFRAMES + tt] : 0.f;
        float m155 = (ok && f >= 155) ? mb[(size_t)(f - 155) * NFRAMES + tt] : 0.f;
        float m0   = ok ? mb[(size_t)f * NFRAMES + tt] : 0.f;
        rows[0][i] = (1.f - fr4) * m336 + fr4 * m337;
        rows[1][i] = (1.f - fr5) * m154 + fr5 * m155;
        rows[2][i] = m0;
    }
    __syncthreads();

    char* crow = (char*)f0c + ((size_t)(b * FROWS + f + 1)) * 840 * 64;

    // left pad zeros: tg in [0,4)
    if (tid < 16) {
        int tg = tid >> 2, q = tid & 3;
        int swz = (((tg >> 1) & 3) << 4) | (((tg >> 3) & 1) << 6);
        f16x8 z;
        #pragma unroll
        for (int j = 0; j < 8; ++j) z[j] = (f16)0.f;
        *reinterpret_cast<f16x8*>(crow + ((tg * 64 + q * 16) ^ swz)) = z;
    }

    #pragma unroll
    for (int chunk = 0; chunk < 4; ++chunk) {
        int t = chunk * 256 + tid;
        if (t < NFRAMES) {
            float win[3][7];
            #pragma unroll
            for (int r = 0; r < 3; ++r)
                #pragma unroll
                for (int k = 0; k < 7; ++k)
                    win[r][k] = rows[r][t + k];

            float vals[32];
            #pragma unroll
            for (int o = 0; o < 32; ++o) {
                float a = bias[o];
                #pragma unroll
                for (int r = 0; r < 3; ++r) {
                    const float* wr = wn + (o * 7 + 4 + r) * 7;
                    #pragma unroll
                    for (int kw = 0; kw < 7; ++kw)
                        a = fmaf(win[r][kw], wr[kw], a);
                }
                vals[o] = (a > 0.f) ? a : 0.1f * a;
            }

            #pragma unroll
            for (int o = 0; o < 32; ++o)
                out[(((size_t)b * 32 + o) * NBINS + f) * (size_t)NFRAMES + t] = vals[o];

            int tg = t + 4;
            int swz = (((tg >> 1) & 3) << 4) | (((tg >> 3) & 1) << 6);
            #pragma unroll
            for (int q = 0; q < 4; ++q) {
                f16x8 h;
                #pragma unroll
                for (int j = 0; j < 8; ++j) h[j] = (f16)vals[q * 8 + j];
                *reinterpret_cast<f16x8*>(crow + ((tg * 64 + q * 16) ^ swz)) = h;
            }
        } else if (t < 836) {                 // right pad zeros: tg in [805,840)
            int tg = t + 4;
            int swz = (((tg >> 1) & 3) << 4) | (((tg >> 3) & 1) << 6);
            f16x8 z;
            #pragma unroll
            for (int j = 0; j < 8; ++j) z[j] = (f16)0.f;
            #pragma unroll
            for (int q = 0; q < 4; ++q)
                *reinterpret_cast<f16x8*>(crow + ((tg * 64 + q * 16) ^ swz)) = z;
        }
    }
}

// ------------------------------------------------- pipelined MFMA conv ----
// 32ch -> 32ch via mfma_f32_32x32x16_f16. One block per (4 f-rows, b) strip,
// looping over NTB t-tiles (NT=32) with double-buffered LDS and a 2-phase
// pipeline: issue next-tile loads (regs) -> compute current (ds_read+MFMA)
// -> stores -> ds_write staged regs -> one __syncthreads per tile.
// Input: padded swizzle-baked fp16 copy [b][f+1][TpadIn][32c] with guard
// rows; staging is branch-free (f=512-edge over-reads land in ws, discarded).
template<int KW, int STRIDE, int PW, int PAD_IN, int PAD_OUT, int NTB, bool DO_LRELU>
__global__ __launch_bounds__(256, 2) void conv_v4(
    const f16* __restrict__ inC, const f16* __restrict__ Ap,
    const float* __restrict__ bias, float* __restrict__ out,
    f16* __restrict__ outC, int Tout, int TpadIn, int TpadOut)
{
    constexpr int NT   = 32;
    constexpr int TR   = NT * STRIDE + KW - 1;
    constexpr int TRP  = (TR + 1) & ~1;
    constexpr int ROWB = TRP * 64;
    constexpr int BUFB = 6 * ROWB;
    constexpr int SL   = BUFB / 16;            // 16B slots per buffer
    constexpr int KPT  = (SL + 255) / 256;
    constexpr int TOFF = (PAD_IN - PW) & 15;

    __shared__ char ldsb[2 * BUFB];

    const int tid  = threadIdx.x;
    const int lane = tid & 63;
    const int wave = tid >> 6;

    // XCD-aware bijective swizzle: consecutive work ids (f-major) per XCD.
    const int NWG = 129 * 4;
    int l0 = blockIdx.x;
    int xcd = l0 & 7, sl = l0 >> 3;
    const int q = NWG / 8, r = NWG % 8;        // 64, 4
    int work = (xcd < r ? xcd * (q + 1) : r * (q + 1) + (xcd - r) * q) + sl;
    const int b    = work / 129;
    const int fblk = work - b * 129;
    const int f0   = fblk * 4;
    const int brow = b * FROWS + f0;           // row of fr=0 (fi=f0-1 -> +1)

    // per-thread staging slot decomposition (tile-invariant)
    size_t sbase[KPT];
    #pragma unroll
    for (int k = 0; k < KPT; ++k) {
        int s = tid + k * 256;
        int fr = s / (TRP * 4);
        int s2 = s - fr * (TRP * 4);
        sbase[k] = ((size_t)(brow + fr) * TpadIn) * 64 + (size_t)s2 * 16;
    }

    f16x8 stg[KPT];
    const char* inB = (const char*)inC;

    auto issue = [&](int tb) {
        size_t g0b = (size_t)(tb * (NT * STRIDE) + (PAD_IN - PW)) * 64;
        #pragma unroll
        for (int k = 0; k < KPT; ++k) {
            if (KPT * 256 == SL || tid + k * 256 < SL)
                stg[k] = *reinterpret_cast<const f16x8*>(inB + sbase[k] + g0b);
        }
    };
    auto commit = [&](int bufsel) {
        #pragma unroll
        for (int k = 0; k < KPT; ++k) {
            int s = tid + k * 256;
            if (KPT * 256 == SL || s < SL)
                *reinterpret_cast<f16x8*>(ldsb + bufsel * BUFB + s * 16) = stg[k];
        }
    };

    // swizzled LDS read bases
    const int tln = lane & 31;
    const int hi  = lane >> 5;
    int baddr0[KW];
    #pragma unroll
    for (int kw = 0; kw < KW; ++kw) {
        int trow = tln * STRIDE + kw;
        int x = trow + TOFF;
        int swz = (((x >> 1) & 3) << 4) | (((x >> 3) & 1) << 6);
        baddr0[kw] = (trow * 64 + hi * 16) ^ swz;
    }

    float bs[16];
    #pragma unroll
    for (int rr = 0; rr < 16; ++rr) bs[rr] = bias[4 * hi + 8 * (rr >> 2) + (rr & 3)];

    const int f = f0 + wave;
    char* crow = nullptr;
    if constexpr (PAD_OUT > 0)
        crow = (char*)outC + ((size_t)(b * FROWS + f + 1)) * TpadOut * 64;

    issue(0);
    commit(0);
    __syncthreads();
    int cur = 0;

    #pragma unroll 1
    for (int tb = 0; tb < NTB; ++tb) {
        if (tb + 1 < NTB) issue(tb + 1);      // loads in flight through compute

        f32x16 acc;
        #pragma unroll
        for (int rr = 0; rr < 16; ++rr) acc[rr] = 0.f;

        const char* lbase = ldsb + cur * BUFB + wave * ROWB;
        #pragma unroll
        for (int df = 0; df < 3; ++df) {
            f16x8 a[KW * 2];
            #pragma unroll
            for (int kw = 0; kw < KW; ++kw)
                #pragma unroll
                for (int ch = 0; ch < 2; ++ch)
                    a[kw * 2 + ch] = *reinterpret_cast<const f16x8*>(
                        Ap + (((df * KW + kw) * 2 + ch) << 9) + lane * 8);
            #pragma unroll
            for (int kw = 0; kw < KW; ++kw)
                #pragma unroll
                for (int ch = 0; ch < 2; ++ch) {
                    f16x8 bf = *reinterpret_cast<const f16x8*>(
                        lbase + (baddr0[kw] ^ (ch << 5)) + df * ROWB);
                    acc = __builtin_amdgcn_mfma_f32_32x32x16_f16(a[kw * 2 + ch], bf, acc, 0, 0, 0);
                }
        }

        if (f < NBINS) {
            int t = tb * NT + tln;
            bool vt = (t < Tout);
            float vals[16];
            #pragma unroll
            for (int rr = 0; rr < 16; ++rr) {
                float v = acc[rr] + bs[rr];
                if (DO_LRELU) v = (v > 0.f) ? v : 0.1f * v;
                vals[rr] = v;
            }
            if (vt) {
                #pragma unroll
                for (int rr = 0; rr < 16; ++rr) {
                    int o = 4 * hi + 8 * (rr >> 2) + (rr & 3);
                    out[(((size_t)b * 32 + o) * NBINS + f) * Tout + t] = vals[rr];
                }
            }
            if constexpr (PAD_OUT > 0) {
                int tg = t + PAD_OUT;
                int swz = (((tg >> 1) & 3) << 4) | (((tg >> 3) & 1) << 6);
                int rowbyte = (tg * 64) ^ swz;
                #pragma unroll
                for (int qq = 0; qq < 4; ++qq) {
                    f16x4 hv;
                    #pragma unroll
                    for (int rr = 0; rr < 4; ++rr)
                        hv[rr] = vt ? (f16)vals[4 * qq + rr] : (f16)0.f;
                    *reinterpret_cast<f16x4*>(crow + (rowbyte ^ ((4 * hi + 8 * qq) << 1))) = hv;
                }
                if (tb == 0 && lane < PAD_OUT * 4) {
                    int tgp = lane >> 2, oct = lane & 3;
                    f16x8 z;
                    #pragma unroll
                    for (int j = 0; j < 8; ++j) z[j] = (f16)0.f;
                    *reinterpret_cast<f16x8*>(crow + tgp * 64 + oct * 16) = z;
                }
            }
        }

        if (tb + 1 < NTB) commit(cur ^ 1);
        __syncthreads();
        cur ^= 1;
    }
}

// ------------------------------------------------------------ final conv ----
__global__ __launch_bounds__(256) void convo_kernel(const float* __restrict__ in,
                                                    const float* __restrict__ wn,
                                                    const float* __restrict__ bias,
                                                    float* __restrict__ f5,
                                                    float* __restrict__ flat)
{
    int idx = blockIdx.x * 256 + threadIdx.x;
    if (idx >= 4 * NBINS * 101) return;
    int t = idx % 101;
    int rem = idx / 101;
    int f = rem % NBINS;
    int b = rem / NBINS;

    float a = bias[0];
    const float* inb = in + (size_t)b * 32 * NBINS * 101;
    for (int c = 0; c < 32; ++c) {
        #pragma unroll
        for (int df = 0; df < 3; ++df) {
            int fi = f + df - 1;
            if (fi < 0 || fi >= NBINS) continue;
            #pragma unroll
            for (int kw = 0; kw < 3; ++kw) {
                int ti = t + kw - 1;
                if (ti < 0 || ti >= 101) continue;
                a = fmaf(inb[((size_t)c * NBINS + fi) * 101 + ti], wn[(c * 3 + df) * 3 + kw], a);
            }
        }
    }
    f5[idx] = a;
    flat[idx] = a;
}

// ------------------------------------------------------------------ launch --
extern "C" void kernel_launch(void* const* d_in, const int* in_sizes, int n_in,
                              void* d_out, int out_size, void* d_ws, size_t ws_size,
                              hipStream_t stream)
{
    const float* y  = (const float*)d_in[0];
    const float* v0 = (const float*)d_in[1];
    const float* g0 = (const float*)d_in[2];
    const float* b0 = (const float*)d_in[3];
    const float* v1 = (const float*)d_in[4];
    const float* g1 = (const float*)d_in[5];
    const float* b1 = (const float*)d_in[6];
    const float* v2 = (const float*)d_in[7];
    const float* g2 = (const float*)d_in[8];
    const float* b2 = (const float*)d_in[9];
    const float* v3 = (const float*)d_in[10];
    const float* g3 = (const float*)d_in[11];
    const float* b3 = (const float*)d_in[12];
    const float* v4 = (const float*)d_in[13];
    const float* g4 = (const float*)d_in[14];
    const float* b4 = (const float*)d_in[15];
    const float* vo = (const float*)d_in[16];
    const float* go = (const float*)d_in[17];
    const float* bo = (const float*)d_in[18];

    float* out = (float*)d_out;
    float* ws  = (float*)d_ws;

    const size_t SFLAT = (size_t)4 * NBINS * 101;
    const size_t NF0   = (size_t)4 * 32 * NBINS * 801;
    const size_t NF1   = (size_t)4 * 32 * NBINS * 401;
    const size_t NF2   = (size_t)4 * 32 * NBINS * 201;
    const size_t NF3   = (size_t)4 * 32 * NBINS * 101;
    float* oflat = out;
    float* f0 = out + SFLAT;
    float* f1 = f0 + NF0;
    float* f2 = f1 + NF1;
    float* f3 = f2 + NF2;
    float* f4 = f3 + NF3;
    float* f5 = f4 + NF3;

    // mag stashed in (not-yet-written) fmap1 region; consumed before conv1 writes it
    float* mag = f1;

    // ws layout: fp32 small weights, fp16 A-packs, fp16 activation copies
    const int TP0 = 840, TP1 = 456, TP2 = 264, TP3 = 136;
    size_t off = 0;
    float* w0n = ws + off; off += 1568;
    float* won = ws + off; off += 288;
    f16* A1 = (f16*)(ws + off);
    f16* A2 = A1 + 27648;
    f16* A3 = A2 + 27648;
    f16* A4 = A3 + 27648;               // 9216 elements
    f16* f0c = A4 + 9216;               // [4][515][840][32]
    f16* f1c = f0c + (size_t)4 * FROWS * TP0 * 32;   // [4][515][456][32]
    f16* f2c = f1c + (size_t)4 * FROWS * TP1 * 32;   // [4][515][264][32]
    f16* f3c = f2c + (size_t)4 * FROWS * TP2 * 32;   // [4][515][136][32]

    zero_pads<<<dim3(256, 4), 256, 0, stream>>>(f0c, f1c, f2c, f3c);

    prep_kernel<<<161, 256, 0, stream>>>(v0, g0, v1, g1, v2, g2, v3, g3,
                                         v4, g4, vo, go, w0n, won,
                                         A1, A2, A3, A4);

    stft_kernel<<<dim3(NFRAMES, 4), 512, 0, stream>>>(y, mag);

    double sh4 = -(1000.0 * log(0.001 * (5.0 / 7.0)) - 1000.0 * log(0.001)); // 336.472...
    double sh5 = -(1000.0 * log(0.001 * (6.0 / 7.0)) - 1000.0 * log(0.001)); // 154.150...
    float fr4 = (float)(sh4 - floor(sh4));
    float fr5 = (float)(sh5 - floor(sh5));

    harmonic_kernel<<<dim3(NBINS, 4), 256, 0, stream>>>(mag, w0n, b0, f0, f0c, fr4, fr5);

    // conv chain: pipelined, fp16-copy in, fp32 fmap out (+ copy for next)
    conv_v4<9, 2, 4, 4, 4, 13, true><<<516, 256, 0, stream>>>(f0c, A1, b1, f1, f1c, 401, TP0, TP1);
    conv_v4<9, 2, 4, 4, 4,  7, true><<<516, 256, 0, stream>>>(f1c, A2, b2, f2, f2c, 201, TP1, TP2);
    conv_v4<9, 2, 4, 4, 5,  4, true><<<516, 256, 0, stream>>>(f2c, A3, b3, f3, f3c, 101, TP2, TP3);
    conv_v4<3, 1, 1, 5, 0,  4, true><<<516, 256, 0, stream>>>(f3c, A4, b4, f4, nullptr, 101, TP3, 0);

    convo_kernel<<<(int)((4 * NBINS * 101 + 255) / 256), 256, 0, stream>>>(f4, won, bo, f5, oflat);
}

// Round 10
// 801.186 us; speedup vs baseline: 1.2175x; 1.2175x over previous
//
#include <hip/hip_runtime.h>
#include <math.h>

#define T_SAMPLES 96000
#define NFRAMES 801
#define NBINS 513
#define FROWS 515   // NBINS + 2 guard rows (index f+1; rows 0 and 514 are zero)
#define EPS32 1.1920928955078125e-07f

typedef _Float16 f16;
typedef f16 f16x2 __attribute__((ext_vector_type(2)));
typedef f16 f16x4 __attribute__((ext_vector_type(4)));
typedef f16 f16x8 __attribute__((ext_vector_type(8)));
typedef float f32x4 __attribute__((ext_vector_type(4)));
typedef float f32x16 __attribute__((ext_vector_type(16)));

// ---------------------------------------------------------------- STFT ----
__global__ __launch_bounds__(512) void stft_kernel(const float* __restrict__ y,
                                                   float* __restrict__ mag)
{
    int t = blockIdx.x;   // frame 0..800
    int b = blockIdx.y;   // batch 0..3
    int tid = threadIdx.x;

    __shared__ float2 buf[2][1024];

    const float* yb = y + (size_t)b * T_SAMPLES;
    for (int n = tid; n < 1024; n += 512) {
        int j = t * 120 + n - 512;          // reflect pad 512 both sides
        if (j < 0) j = -j;
        if (j >= T_SAMPLES) j = 2 * T_SAMPLES - 2 - j;
        float v = yb[j];
        int np_ = n - 212;                  // window placed at lp=212, len 600
        float w = 0.0f;
        if (np_ >= 0 && np_ < 600)
            w = 0.5f * (1.0f - cospif((float)np_ * (1.0f / 300.0f)));
        buf[0][n] = make_float2(v * w, 0.0f);
    }
    __syncthreads();

    int srcb = 0;
    #pragma unroll
    for (int stage = 0; stage < 10; ++stage) {
        int m  = 1 << stage;
        int jm = (tid >> stage) << stage;   // j*m
        float jf = (float)jm * (1.0f / 512.0f);
        float wr = cospif(jf);
        float wi = -sinpif(jf);             // e^{-i pi j/l}
        float2 a  = buf[srcb][tid];
        float2 bb = buf[srcb][tid + 512];
        float2 s  = make_float2(a.x + bb.x, a.y + bb.y);
        float2 d  = make_float2(a.x - bb.x, a.y - bb.y);
        float2 dw = make_float2(d.x * wr - d.y * wi, d.x * wi + d.y * wr);
        buf[srcb ^ 1][tid + jm]     = s;
        buf[srcb ^ 1][tid + jm + m] = dw;
        __syncthreads();
        srcb ^= 1;
    }

    float2 v = buf[srcb][tid];
    float msq = v.x * v.x + v.y * v.y;
    mag[((size_t)b * NBINS + tid) * NFRAMES + t] = sqrtf(fmaxf(msq, EPS32));
    if (tid == 0) {
        float2 v5 = buf[srcb][512];
        float m5 = v5.x * v5.x + v5.y * v5.y;
        mag[((size_t)b * NBINS + 512) * NFRAMES + t] = sqrtf(fmaxf(m5, EPS32));
    }
}

// ----------------------------------------------------------- zero pads ----
__global__ __launch_bounds__(256) void zero_pads(f16* p0, f16* p1, f16* p2, f16* p3)
{
    const int TPs[4]   = {840, 456, 264, 136};
    const int tails[4] = {840, 420, 228, 133};   // L0 tail covered by harmonic
    f16* ptrs[4] = {p0, p1, p2, p3};
    int l = blockIdx.y;
    f16* p = ptrs[l];
    int TP = TPs[l], tail = tails[l];
    int rowSlots   = TP * 4;                      // 16B slots per row
    int guardSlots = 8 * rowSlots;                // 4b x {0,514}
    int tailCols   = TP - tail;
    int tailSlots  = 4 * FROWS * tailCols * 4;
    int total = guardSlots + tailSlots;
    f16x8 z;
    #pragma unroll
    for (int j = 0; j < 8; ++j) z[j] = (f16)0.f;
    for (int i = blockIdx.x * 256 + threadIdx.x; i < total; i += gridDim.x * 256) {
        size_t slot;
        if (i < guardSlots) {
            int rs = i / rowSlots;
            int q  = i - rs * rowSlots;
            int b  = rs >> 1;
            int r  = (rs & 1) ? (FROWS - 1) : 0;
            slot = ((size_t)(b * FROWS + r)) * rowSlots + q;
        } else {
            int j2 = i - guardSlots;
            int per = tailCols * 4;
            int row = j2 / per;
            int q   = j2 - row * per;
            slot = ((size_t)row * TP + tail) * 4 + q;
        }
        *reinterpret_cast<f16x8*>((char*)p + slot * 16) = z;
    }
}

// -------------------------------------------------- fused weight prep ----
__global__ __launch_bounds__(256) void prep_kernel(
    const float* __restrict__ v0, const float* __restrict__ g0,
    const float* __restrict__ v1, const float* __restrict__ g1,
    const float* __restrict__ v2, const float* __restrict__ g2,
    const float* __restrict__ v3, const float* __restrict__ g3,
    const float* __restrict__ v4, const float* __restrict__ g4,
    const float* __restrict__ vo, const float* __restrict__ go,
    float* __restrict__ w0n, float* __restrict__ won,
    f16* __restrict__ A1, f16* __restrict__ A2,
    f16* __restrict__ A3, f16* __restrict__ A4)
{
    int blk = blockIdx.x;
    int tid = threadIdx.x;

    const float *v, *g; f16* Ap = nullptr; float* outf = nullptr;
    int o, per_o, KW = 9;
    if (blk < 32)        { v = v1; g = g1; Ap = A1; o = blk;       per_o = 864; }
    else if (blk < 64)   { v = v2; g = g2; Ap = A2; o = blk - 32;  per_o = 864; }
    else if (blk < 96)   { v = v3; g = g3; Ap = A3; o = blk - 64;  per_o = 864; }
    else if (blk < 128)  { v = v4; g = g4; Ap = A4; o = blk - 96;  per_o = 288; KW = 3; }
    else if (blk < 160)  { v = v0; g = g0; outf = w0n; o = blk - 128; per_o = 49; }
    else                 { v = vo; g = go; outf = won; o = 0;        per_o = 288; }

    const float* vv = v + (size_t)o * per_o;
    __shared__ float red[256];
    float s = 0.f;
    for (int i = tid; i < per_o; i += 256) { float x = vv[i]; s = fmaf(x, x, s); }
    red[tid] = s;
    __syncthreads();
    for (int k = 128; k > 0; k >>= 1) {
        if (tid < k) red[tid] += red[tid + k];
        __syncthreads();
    }
    float scale = g[o] / sqrtf(red[0]);

    if (outf) {
        for (int i = tid; i < per_o; i += 256)
            outf[(size_t)o * per_o + i] = vv[i] * scale;
    } else {
        for (int i = tid; i < per_o; i += 256) {
            int tap = i >> 5;
            int c   = i & 31;
            int df  = tap / KW, kw = tap - df * KW;
            float val = vv[(c * 3 + df) * KW + kw] * scale;
            int l = ((c >> 3) & 1) * 32 + o;
            int ch = c >> 4;
            int j = c & 7;
            Ap[(((tap * 2 + ch) * 64 + l) << 3) + j] = (f16)val;
        }
    }
}

// -------------------------------------------------------- harmonic conv ----
__global__ __launch_bounds__(256) void harmonic_kernel(const float* __restrict__ mag,
                                                       const float* __restrict__ wn,
                                                       const float* __restrict__ bias,
                                                       float* __restrict__ out,
                                                       f16* __restrict__ f0c,
                                                       float fr4, float fr5)
{
    int f = blockIdx.x;
    int b = blockIdx.y;
    int tid = threadIdx.x;

    __shared__ float rows[3][808];

    const float* mb = mag + (size_t)b * NBINS * NFRAMES;

    for (int i = tid; i < 808; i += 256) {
        int tt = i - 3;
        bool ok = (tt >= 0) && (tt < NFRAMES);
        float m336 = (ok && f >= 336) ? mb[(size_t)(f - 336) * NFRAMES + tt] : 0.f;
        float m337 = (ok && f >= 337) ? mb[(size_t)(f - 337) * NFRAMES + tt] : 0.f;
        float m154 = (ok && f >= 154) ? mb[(size_t)(f - 154) * NFRAMES + tt] : 0.f;
        float m155 = (ok && f >= 155) ? mb[(size_t)(f - 155) * NFRAMES + tt] : 0.f;
        float m0   = ok ? mb[(size_t)f * NFRAMES + tt] : 0.f;
        rows[0][i] = (1.f - fr4) * m336 + fr4 * m337;
        rows[1][i] = (1.f - fr5) * m154 + fr5 * m155;
        rows[2][i] = m0;
    }
    __syncthreads();

    char* crow = (char*)f0c + ((size_t)(b * FROWS + f + 1)) * 840 * 64;

    // left pad zeros: tg in [0,4)
    if (tid < 16) {
        int tg = tid >> 2, q = tid & 3;
        int swz = (((tg >> 1) & 3) << 4) | (((tg >> 3) & 1) << 6);
        f16x8 z;
        #pragma unroll
        for (int j = 0; j < 8; ++j) z[j] = (f16)0.f;
        *reinterpret_cast<f16x8*>(crow + ((tg * 64 + q * 16) ^ swz)) = z;
    }

    #pragma unroll
    for (int chunk = 0; chunk < 4; ++chunk) {
        int t = chunk * 256 + tid;
        if (t < NFRAMES) {
            float win[3][7];
            #pragma unroll
            for (int r = 0; r < 3; ++r)
                #pragma unroll
                for (int k = 0; k < 7; ++k)
                    win[r][k] = rows[r][t + k];

            float vals[32];
            #pragma unroll
            for (int o = 0; o < 32; ++o) {
                float a = bias[o];
                #pragma unroll
                for (int r = 0; r < 3; ++r) {
                    const float* wr = wn + (o * 7 + 4 + r) * 7;
                    #pragma unroll
                    for (int kw = 0; kw < 7; ++kw)
                        a = fmaf(win[r][kw], wr[kw], a);
                }
                vals[o] = (a > 0.f) ? a : 0.1f * a;
            }

            #pragma unroll
            for (int o = 0; o < 32; ++o)
                out[(((size_t)b * 32 + o) * NBINS + f) * (size_t)NFRAMES + t] = vals[o];

            int tg = t + 4;
            int swz = (((tg >> 1) & 3) << 4) | (((tg >> 3) & 1) << 6);
            #pragma unroll
            for (int q = 0; q < 4; ++q) {
                f16x8 h;
                #pragma unroll
                for (int j = 0; j < 8; ++j) h[j] = (f16)vals[q * 8 + j];
                *reinterpret_cast<f16x8*>(crow + ((tg * 64 + q * 16) ^ swz)) = h;
            }
        } else if (t < 836) {                 // right pad zeros: tg in [805,840)
            int tg = t + 4;
            int swz = (((tg >> 1) & 3) << 4) | (((tg >> 3) & 1) << 6);
            f16x8 z;
            #pragma unroll
            for (int j = 0; j < 8; ++j) z[j] = (f16)0.f;
            #pragma unroll
            for (int q = 0; q < 4; ++q)
                *reinterpret_cast<f16x8*>(crow + ((tg * 64 + q * 16) ^ swz)) = z;
        }
    }
}

// ------------------------------------------- pipelined MFMA conv (v5) ----
// Same tiling as v4 but staging goes through global_load_lds (direct
// global->LDS DMA): zero staging VGPRs, so the compute phase keeps the
// conv_v3 register footprint and nothing spills. Per tile: issue next-tile
// gload_lds into buf^1 -> compute current (ds_read+MFMA) -> stores ->
// __syncthreads (its vmcnt(0) drains the in-flight loads) -> swap.
template<int KW, int STRIDE, int PW, int PAD_IN, int PAD_OUT, int NTB, bool DO_LRELU>
__global__ __launch_bounds__(256, 2) void conv_v5(
    const f16* __restrict__ inC, const f16* __restrict__ Ap,
    const float* __restrict__ bias, float* __restrict__ out,
    f16* __restrict__ outC, int Tout, int TpadIn, int TpadOut)
{
    constexpr int NT   = 32;
    constexpr int TR   = NT * STRIDE + KW - 1;
    constexpr int TRP  = (TR + 7) & ~7;        // %8 -> SL % 64 == 0 (uniform masks)
    constexpr int ROWB = TRP * 64;
    constexpr int SL   = 6 * TRP * 4;          // active 16B slots per tile
    constexpr int KPT  = (SL + 255) / 256;
    constexpr int BUFB = KPT * 256 * 16;       // padded buffer (tail group slack)
    constexpr int TOFF = (PAD_IN - PW) & 15;

    __shared__ char ldsb[2 * BUFB];

    const int tid  = threadIdx.x;
    const int lane = tid & 63;
    const int wave = tid >> 6;

    // XCD-aware bijective swizzle: consecutive work ids (f-major) per XCD.
    const int NWG = 129 * 4;
    int l0 = blockIdx.x;
    int xcd = l0 & 7, sl = l0 >> 3;
    const int q = NWG / 8, r = NWG % 8;        // 64, 4
    int work = (xcd < r ? xcd * (q + 1) : r * (q + 1) + (xcd - r) * q) + sl;
    const int b    = work / 129;
    const int fblk = work - b * 129;
    const int f0   = fblk * 4;
    const int brow = b * FROWS + f0;           // fi=f0-1 -> copy row brow (guards)

    // per-thread tile-invariant global byte offsets (tb=0)
    const char* inB = (const char*)inC;
    unsigned goff[KPT];
    #pragma unroll
    for (int k = 0; k < KPT; ++k) {
        int s = tid + k * 256;
        int fr = s / (TRP * 4);
        int s2 = s - fr * (TRP * 4);
        goff[k] = (unsigned)(((brow + fr) * TpadIn + (PAD_IN - PW)) * 64 + s2 * 16);
    }

    auto issue = [&](int tb, int bufsel) {
        unsigned add = (unsigned)(tb * NT * STRIDE) * 64u;
        #pragma unroll
        for (int k = 0; k < KPT; ++k) {
            if (KPT * 256 == SL || tid + k * 256 < SL) {   // wave-uniform
                __builtin_amdgcn_global_load_lds(
                    (const __attribute__((address_space(1))) void*)(inB + goff[k] + add),
                    (__attribute__((address_space(3))) void*)(ldsb + bufsel * BUFB + (k * 256 + (tid & 192)) * 16),
                    16, 0, 0);
            }
        }
    };

    // swizzled LDS read bases
    const int tln = lane & 31;
    const int hi  = lane >> 5;
    int baddr0[KW];
    #pragma unroll
    for (int kw = 0; kw < KW; ++kw) {
        int trow = tln * STRIDE + kw;
        int x = trow + TOFF;
        int swz = (((x >> 1) & 3) << 4) | (((x >> 3) & 1) << 6);
        baddr0[kw] = (trow * 64 + hi * 16) ^ swz;
    }

    float bs[16];
    #pragma unroll
    for (int rr = 0; rr < 16; ++rr) bs[rr] = bias[4 * hi + 8 * (rr >> 2) + (rr & 3)];

    const int f = f0 + wave;
    char* crow = nullptr;
    if constexpr (PAD_OUT > 0)
        crow = (char*)outC + ((size_t)(b * FROWS + f + 1)) * TpadOut * 64;

    issue(0, 0);
    __syncthreads();
    int cur = 0;

    #pragma unroll 1
    for (int tb = 0; tb < NTB; ++tb) {
        if (tb + 1 < NTB) issue(tb + 1, cur ^ 1);   // in flight through compute

        f32x16 acc;
        #pragma unroll
        for (int rr = 0; rr < 16; ++rr) acc[rr] = 0.f;

        const char* lbase = ldsb + cur * BUFB + wave * ROWB;
        #pragma unroll
        for (int df = 0; df < 3; ++df) {
            f16x8 a[KW * 2];
            #pragma unroll
            for (int kw = 0; kw < KW; ++kw)
                #pragma unroll
                for (int ch = 0; ch < 2; ++ch)
                    a[kw * 2 + ch] = *reinterpret_cast<const f16x8*>(
                        Ap + (((df * KW + kw) * 2 + ch) << 9) + lane * 8);
            #pragma unroll
            for (int kw = 0; kw < KW; ++kw)
                #pragma unroll
                for (int ch = 0; ch < 2; ++ch) {
                    f16x8 bf = *reinterpret_cast<const f16x8*>(
                        lbase + (baddr0[kw] ^ (ch << 5)) + df * ROWB);
                    acc = __builtin_amdgcn_mfma_f32_32x32x16_f16(a[kw * 2 + ch], bf, acc, 0, 0, 0);
                }
        }

        if (f < NBINS) {
            int t = tb * NT + tln;
            bool vt = (t < Tout);
            float vals[16];
            #pragma unroll
            for (int rr = 0; rr < 16; ++rr) {
                float v = acc[rr] + bs[rr];
                if (DO_LRELU) v = (v > 0.f) ? v : 0.1f * v;
                vals[rr] = v;
            }
            if (vt) {
                #pragma unroll
                for (int rr = 0; rr < 16; ++rr) {
                    int o = 4 * hi + 8 * (rr >> 2) + (rr & 3);
                    out[(((size_t)b * 32 + o) * NBINS + f) * Tout + t] = vals[rr];
                }
            }
            if constexpr (PAD_OUT > 0) {
                int tg = t + PAD_OUT;
                int swz = (((tg >> 1) & 3) << 4) | (((tg >> 3) & 1) << 6);
                int rowbyte = (tg * 64) ^ swz;
                #pragma unroll
                for (int qq = 0; qq < 4; ++qq) {
                    f16x4 hv;
                    #pragma unroll
                    for (int rr = 0; rr < 4; ++rr)
                        hv[rr] = vt ? (f16)vals[4 * qq + rr] : (f16)0.f;
                    *reinterpret_cast<f16x4*>(crow + (rowbyte ^ ((4 * hi + 8 * qq) << 1))) = hv;
                }
                if (tb == 0 && lane < PAD_OUT * 4) {
                    int tgp = lane >> 2, oct = lane & 3;
                    f16x8 z;
                    #pragma unroll
                    for (int j = 0; j < 8; ++j) z[j] = (f16)0.f;
                    *reinterpret_cast<f16x8*>(crow + tgp * 64 + oct * 16) = z;
                }
            }
        }

        __syncthreads();    // drains vmcnt -> buf^1 ready; everyone done with cur
        cur ^= 1;
    }
}

// ------------------------------------------------------------ final conv ----
__global__ __launch_bounds__(256) void convo_kernel(const float* __restrict__ in,
                                                    const float* __restrict__ wn,
                                                    const float* __restrict__ bias,
                                                    float* __restrict__ f5,
                                                    float* __restrict__ flat)
{
    int idx = blockIdx.x * 256 + threadIdx.x;
    if (idx >= 4 * NBINS * 101) return;
    int t = idx % 101;
    int rem = idx / 101;
    int f = rem % NBINS;
    int b = rem / NBINS;

    float a = bias[0];
    const float* inb = in + (size_t)b * 32 * NBINS * 101;
    for (int c = 0; c < 32; ++c) {
        #pragma unroll
        for (int df = 0; df < 3; ++df) {
            int fi = f + df - 1;
            if (fi < 0 || fi >= NBINS) continue;
            #pragma unroll
            for (int kw = 0; kw < 3; ++kw) {
                int ti = t + kw - 1;
                if (ti < 0 || ti >= 101) continue;
                a = fmaf(inb[((size_t)c * NBINS + fi) * 101 + ti], wn[(c * 3 + df) * 3 + kw], a);
            }
        }
    }
    f5[idx] = a;
    flat[idx] = a;
}

// ------------------------------------------------------------------ launch --
extern "C" void kernel_launch(void* const* d_in, const int* in_sizes, int n_in,
                              void* d_out, int out_size, void* d_ws, size_t ws_size,
                              hipStream_t stream)
{
    const float* y  = (const float*)d_in[0];
    const float* v0 = (const float*)d_in[1];
    const float* g0 = (const float*)d_in[2];
    const float* b0 = (const float*)d_in[3];
    const float* v1 = (const float*)d_in[4];
    const float* g1 = (const float*)d_in[5];
    const float* b1 = (const float*)d_in[6];
    const float* v2 = (const float*)d_in[7];
    const float* g2 = (const float*)d_in[8];
    const float* b2 = (const float*)d_in[9];
    const float* v3 = (const float*)d_in[10];
    const float* g3 = (const float*)d_in[11];
    const float* b3 = (const float*)d_in[12];
    const float* v4 = (const float*)d_in[13];
    const float* g4 = (const float*)d_in[14];
    const float* b4 = (const float*)d_in[15];
    const float* vo = (const float*)d_in[16];
    const float* go = (const float*)d_in[17];
    const float* bo = (const float*)d_in[18];

    float* out = (float*)d_out;
    float* ws  = (float*)d_ws;

    const size_t SFLAT = (size_t)4 * NBINS * 101;
    const size_t NF0   = (size_t)4 * 32 * NBINS * 801;
    const size_t NF1   = (size_t)4 * 32 * NBINS * 401;
    const size_t NF2   = (size_t)4 * 32 * NBINS * 201;
    const size_t NF3   = (size_t)4 * 32 * NBINS * 101;
    float* oflat = out;
    float* f0 = out + SFLAT;
    float* f1 = f0 + NF0;
    float* f2 = f1 + NF1;
    float* f3 = f2 + NF2;
    float* f4 = f3 + NF3;
    float* f5 = f4 + NF3;

    // mag stashed in (not-yet-written) fmap1 region; consumed before conv1 writes it
    float* mag = f1;

    // ws layout: fp32 small weights, fp16 A-packs, fp16 activation copies
    const int TP0 = 840, TP1 = 456, TP2 = 264, TP3 = 136;
    size_t off = 0;
    float* w0n = ws + off; off += 1568;
    float* won = ws + off; off += 288;
    f16* A1 = (f16*)(ws + off);
    f16* A2 = A1 + 27648;
    f16* A3 = A2 + 27648;
    f16* A4 = A3 + 27648;               // 9216 elements
    f16* f0c = A4 + 9216;               // [4][515][840][32]
    f16* f1c = f0c + (size_t)4 * FROWS * TP0 * 32;   // [4][515][456][32]
    f16* f2c = f1c + (size_t)4 * FROWS * TP1 * 32;   // [4][515][264][32]
    f16* f3c = f2c + (size_t)4 * FROWS * TP2 * 32;   // [4][515][136][32]

    zero_pads<<<dim3(256, 4), 256, 0, stream>>>(f0c, f1c, f2c, f3c);

    prep_kernel<<<161, 256, 0, stream>>>(v0, g0, v1, g1, v2, g2, v3, g3,
                                         v4, g4, vo, go, w0n, won,
                                         A1, A2, A3, A4);

    stft_kernel<<<dim3(NFRAMES, 4), 512, 0, stream>>>(y, mag);

    double sh4 = -(1000.0 * log(0.001 * (5.0 / 7.0)) - 1000.0 * log(0.001)); // 336.472...
    double sh5 = -(1000.0 * log(0.001 * (6.0 / 7.0)) - 1000.0 * log(0.001)); // 154.150...
    float fr4 = (float)(sh4 - floor(sh4));
    float fr5 = (float)(sh5 - floor(sh5));

    harmonic_kernel<<<dim3(NBINS, 4), 256, 0, stream>>>(mag, w0n, b0, f0, f0c, fr4, fr5);

    // conv chain: gload_lds-pipelined, fp16-copy in, fp32 fmap out (+ copy)
    conv_v5<9, 2, 4, 4, 4, 13, true><<<516, 256, 0, stream>>>(f0c, A1, b1, f1, f1c, 401, TP0, TP1);
    conv_v5<9, 2, 4, 4, 4,  7, true><<<516, 256, 0, stream>>>(f1c, A2, b2, f2, f2c, 201, TP1, TP2);
    conv_v5<9, 2, 4, 4, 5,  4, true><<<516, 256, 0, stream>>>(f2c, A3, b3, f3, f3c, 101, TP2, TP3);
    conv_v5<3, 1, 1, 5, 0,  4, true><<<516, 256, 0, stream>>>(f3c, A4, b4, f4, nullptr, 101, TP3, 0);

    convo_kernel<<<(int)((4 * NBINS * 101 + 255) / 256), 256, 0, stream>>>(f4, won, bo, f5, oflat);
}

// Round 11
// 428.852 us; speedup vs baseline: 2.2746x; 1.8682x over previous
//
#include <hip/hip_runtime.h>
#include <math.h>

#define T_SAMPLES 96000
#define NFRAMES 801
#define NBINS 513
#define FROWS 515   // NBINS + 2 guard rows (index f+1; rows 0 and 514 are zero)
#define EPS32 1.1920928955078125e-07f

typedef _Float16 f16;
typedef f16 f16x2 __attribute__((ext_vector_type(2)));
typedef f16 f16x4 __attribute__((ext_vector_type(4)));
typedef f16 f16x8 __attribute__((ext_vector_type(8)));
typedef float f32x4 __attribute__((ext_vector_type(4)));
typedef float f32x16 __attribute__((ext_vector_type(16)));

// ---------------------------------------------------------------- STFT ----
__global__ __launch_bounds__(512) void stft_kernel(const float* __restrict__ y,
                                                   float* __restrict__ mag)
{
    int t = blockIdx.x;   // frame 0..800
    int b = blockIdx.y;   // batch 0..3
    int tid = threadIdx.x;

    __shared__ float2 buf[2][1024];

    const float* yb = y + (size_t)b * T_SAMPLES;
    for (int n = tid; n < 1024; n += 512) {
        int j = t * 120 + n - 512;          // reflect pad 512 both sides
        if (j < 0) j = -j;
        if (j >= T_SAMPLES) j = 2 * T_SAMPLES - 2 - j;
        float v = yb[j];
        int np_ = n - 212;                  // window placed at lp=212, len 600
        float w = 0.0f;
        if (np_ >= 0 && np_ < 600)
            w = 0.5f * (1.0f - cospif((float)np_ * (1.0f / 300.0f)));
        buf[0][n] = make_float2(v * w, 0.0f);
    }
    __syncthreads();

    int srcb = 0;
    #pragma unroll
    for (int stage = 0; stage < 10; ++stage) {
        int m  = 1 << stage;
        int jm = (tid >> stage) << stage;   // j*m
        float jf = (float)jm * (1.0f / 512.0f);
        float wr = cospif(jf);
        float wi = -sinpif(jf);             // e^{-i pi j/l}
        float2 a  = buf[srcb][tid];
        float2 bb = buf[srcb][tid + 512];
        float2 s  = make_float2(a.x + bb.x, a.y + bb.y);
        float2 d  = make_float2(a.x - bb.x, a.y - bb.y);
        float2 dw = make_float2(d.x * wr - d.y * wi, d.x * wi + d.y * wr);
        buf[srcb ^ 1][tid + jm]     = s;
        buf[srcb ^ 1][tid + jm + m] = dw;
        __syncthreads();
        srcb ^= 1;
    }

    float2 v = buf[srcb][tid];
    float msq = v.x * v.x + v.y * v.y;
    mag[((size_t)b * NBINS + tid) * NFRAMES + t] = sqrtf(fmaxf(msq, EPS32));
    if (tid == 0) {
        float2 v5 = buf[srcb][512];
        float m5 = v5.x * v5.x + v5.y * v5.y;
        mag[((size_t)b * NBINS + 512) * NFRAMES + t] = sqrtf(fmaxf(m5, EPS32));
    }
}

// ----------------------------------------------------------- zero pads ----
__global__ __launch_bounds__(256) void zero_pads(f16* p0, f16* p1, f16* p2, f16* p3)
{
    const int TPs[4]   = {840, 456, 264, 136};
    const int tails[4] = {840, 420, 228, 133};   // L0 tail covered by harmonic
    f16* ptrs[4] = {p0, p1, p2, p3};
    int l = blockIdx.y;
    f16* p = ptrs[l];
    int TP = TPs[l], tail = tails[l];
    int rowSlots   = TP * 4;                      // 16B slots per row
    int guardSlots = 8 * rowSlots;                // 4b x {0,514}
    int tailCols   = TP - tail;
    int tailSlots  = 4 * FROWS * tailCols * 4;
    int total = guardSlots + tailSlots;
    f16x8 z;
    #pragma unroll
    for (int j = 0; j < 8; ++j) z[j] = (f16)0.f;
    for (int i = blockIdx.x * 256 + threadIdx.x; i < total; i += gridDim.x * 256) {
        size_t slot;
        if (i < guardSlots) {
            int rs = i / rowSlots;
            int q  = i - rs * rowSlots;
            int b  = rs >> 1;
            int r  = (rs & 1) ? (FROWS - 1) : 0;
            slot = ((size_t)(b * FROWS + r)) * rowSlots + q;
        } else {
            int j2 = i - guardSlots;
            int per = tailCols * 4;
            int row = j2 / per;
            int q   = j2 - row * per;
            slot = ((size_t)row * TP + tail) * 4 + q;
        }
        *reinterpret_cast<f16x8*>((char*)p + slot * 16) = z;
    }
}

// -------------------------------------------------- fused weight prep ----
__global__ __launch_bounds__(256) void prep_kernel(
    const float* __restrict__ v0, const float* __restrict__ g0,
    const float* __restrict__ v1, const float* __restrict__ g1,
    const float* __restrict__ v2, const float* __restrict__ g2,
    const float* __restrict__ v3, const float* __restrict__ g3,
    const float* __restrict__ v4, const float* __restrict__ g4,
    const float* __restrict__ vo, const float* __restrict__ go,
    float* __restrict__ w0n, float* __restrict__ won,
    f16* __restrict__ A1, f16* __restrict__ A2,
    f16* __restrict__ A3, f16* __restrict__ A4)
{
    int blk = blockIdx.x;
    int tid = threadIdx.x;

    const float *v, *g; f16* Ap = nullptr; float* outf = nullptr;
    int o, per_o, KW = 9;
    if (blk < 32)        { v = v1; g = g1; Ap = A1; o = blk;       per_o = 864; }
    else if (blk < 64)   { v = v2; g = g2; Ap = A2; o = blk - 32;  per_o = 864; }
    else if (blk < 96)   { v = v3; g = g3; Ap = A3; o = blk - 64;  per_o = 864; }
    else if (blk < 128)  { v = v4; g = g4; Ap = A4; o = blk - 96;  per_o = 288; KW = 3; }
    else if (blk < 160)  { v = v0; g = g0; outf = w0n; o = blk - 128; per_o = 49; }
    else                 { v = vo; g = go; outf = won; o = 0;        per_o = 288; }

    const float* vv = v + (size_t)o * per_o;
    __shared__ float red[256];
    float s = 0.f;
    for (int i = tid; i < per_o; i += 256) { float x = vv[i]; s = fmaf(x, x, s); }
    red[tid] = s;
    __syncthreads();
    for (int k = 128; k > 0; k >>= 1) {
        if (tid < k) red[tid] += red[tid + k];
        __syncthreads();
    }
    float scale = g[o] / sqrtf(red[0]);

    if (outf) {
        for (int i = tid; i < per_o; i += 256)
            outf[(size_t)o * per_o + i] = vv[i] * scale;
    } else {
        for (int i = tid; i < per_o; i += 256) {
            int tap = i >> 5;
            int c   = i & 31;
            int df  = tap / KW, kw = tap - df * KW;
            float val = vv[(c * 3 + df) * KW + kw] * scale;
            int l = ((c >> 3) & 1) * 32 + o;
            int ch = c >> 4;
            int j = c & 7;
            Ap[(((tap * 2 + ch) * 64 + l) << 3) + j] = (f16)val;
        }
    }
}

// -------------------------------------------------------- harmonic conv ----
__global__ __launch_bounds__(256) void harmonic_kernel(const float* __restrict__ mag,
                                                       const float* __restrict__ wn,
                                                       const float* __restrict__ bias,
                                                       float* __restrict__ out,
                                                       f16* __restrict__ f0c,
                                                       float fr4, float fr5)
{
    int f = blockIdx.x;
    int b = blockIdx.y;
    int tid = threadIdx.x;

    __shared__ float rows[3][808];

    const float* mb = mag + (size_t)b * NBINS * NFRAMES;

    for (int i = tid; i < 808; i += 256) {
        int tt = i - 3;
        bool ok = (tt >= 0) && (tt < NFRAMES);
        float m336 = (ok && f >= 336) ? mb[(size_t)(f - 336) * NFRAMES + tt] : 0.f;
        float m337 = (ok && f >= 337) ? mb[(size_t)(f - 337) * NFRAMES + tt] : 0.f;
        float m154 = (ok && f >= 154) ? mb[(size_t)(f - 154) * NFRAMES + tt] : 0.f;
        float m155 = (ok && f >= 155) ? mb[(size_t)(f - 155) * NFRAMES + tt] : 0.f;
        float m0   = ok ? mb[(size_t)f * NFRAMES + tt] : 0.f;
        rows[0][i] = (1.f - fr4) * m336 + fr4 * m337;
        rows[1][i] = (1.f - fr5) * m154 + fr5 * m155;
        rows[2][i] = m0;
    }
    __syncthreads();

    char* crow = (char*)f0c + ((size_t)(b * FROWS + f + 1)) * 840 * 64;

    // left pad zeros: tg in [0,4)
    if (tid < 16) {
        int tg = tid >> 2, q = tid & 3;
        int swz = (((tg >> 1) & 3) << 4) | (((tg >> 3) & 1) << 6);
        f16x8 z;
        #pragma unroll
        for (int j = 0; j < 8; ++j) z[j] = (f16)0.f;
        *reinterpret_cast<f16x8*>(crow + ((tg * 64 + q * 16) ^ swz)) = z;
    }

    #pragma unroll
    for (int chunk = 0; chunk < 4; ++chunk) {
        int t = chunk * 256 + tid;
        if (t < NFRAMES) {
            float win[3][7];
            #pragma unroll
            for (int r = 0; r < 3; ++r)
                #pragma unroll
                for (int k = 0; k < 7; ++k)
                    win[r][k] = rows[r][t + k];

            float vals[32];
            #pragma unroll
            for (int o = 0; o < 32; ++o) {
                float a = bias[o];
                #pragma unroll
                for (int r = 0; r < 3; ++r) {
                    const float* wr = wn + (o * 7 + 4 + r) * 7;
                    #pragma unroll
                    for (int kw = 0; kw < 7; ++kw)
                        a = fmaf(win[r][kw], wr[kw], a);
                }
                vals[o] = (a > 0.f) ? a : 0.1f * a;
            }

            #pragma unroll
            for (int o = 0; o < 32; ++o)
                out[(((size_t)b * 32 + o) * NBINS + f) * (size_t)NFRAMES + t] = vals[o];

            int tg = t + 4;
            int swz = (((tg >> 1) & 3) << 4) | (((tg >> 3) & 1) << 6);
            #pragma unroll
            for (int q = 0; q < 4; ++q) {
                f16x8 h;
                #pragma unroll
                for (int j = 0; j < 8; ++j) h[j] = (f16)vals[q * 8 + j];
                *reinterpret_cast<f16x8*>(crow + ((tg * 64 + q * 16) ^ swz)) = h;
            }
        } else if (t < 836) {                 // right pad zeros: tg in [805,840)
            int tg = t + 4;
            int swz = (((tg >> 1) & 3) << 4) | (((tg >> 3) & 1) << 6);
            f16x8 z;
            #pragma unroll
            for (int j = 0; j < 8; ++j) z[j] = (f16)0.f;
            #pragma unroll
            for (int q = 0; q < 4; ++q)
                *reinterpret_cast<f16x8*>(crow + ((tg * 64 + q * 16) ^ swz)) = z;
        }
    }
}

// ------------------------------------------------ one-shot MFMA conv v6 ----
// Round-8 structure (one tile per block, full-grid TLP) with two upgrades:
// (a) stage via global_load_lds (zero staging VGPRs, no stage VALU; linear
//     LDS dest + per-lane global source into the baked-swizzle fp16 copy);
// (b) m204 bijective XCD swizzle, tb-fastest work order: the NTB t-tiles of
//     one f-strip share their 6-row input panel in the XCD's L2.
// Guard rows + padded issue groups make staging fully branch-free; over-reads
// land in ws and feed only discarded outputs.
template<int KW, int STRIDE, int PW, int PAD_IN, int PAD_OUT, int NTB, bool DO_LRELU>
__global__ __launch_bounds__(256, 3) void conv_v6(
    const f16* __restrict__ inC, const f16* __restrict__ Ap,
    const float* __restrict__ bias, float* __restrict__ out,
    f16* __restrict__ outC, int Tout, int TpadIn, int TpadOut)
{
    constexpr int NT    = 64;
    constexpr int TR    = NT * STRIDE + KW - 1;
    constexpr int TRP   = (TR + 1) & ~1;
    constexpr int ROWB  = TRP * 64;
    constexpr int SLR   = TRP * 4;             // 16B slots per f-row
    constexpr int SL    = 6 * SLR;             // active slots
    constexpr int KPT   = (SL + 255) / 256;    // issue groups (unconditional)
    constexpr int TOFF  = (PAD_IN - PW) & 15;
    constexpr int NFOFF = 32 * STRIDE * 64;

    __shared__ char ldsb[KPT * 256 * 16];      // padded: slack absorbs tail group

    const int tid  = threadIdx.x;
    const int lane = tid & 63;
    const int wave = tid >> 6;

    // bijective XCD swizzle (m204), work order: tb fastest, then fblk, then b
    const int NWG = NTB * 129 * 4;
    int lin = blockIdx.x;
    int xcd = lin & 7, sl = lin >> 3;
    const int q = NWG / 8, r = NWG % 8;
    int work = (xcd < r ? xcd * (q + 1) : r * (q + 1) + (xcd - r) * q) + sl;
    const int tb   = work % NTB;
    int rem        = work / NTB;
    const int fblk = rem % 129;
    const int b    = rem / 129;
    const int f0   = fblk * 4;
    const int brow = b * FROWS + f0;           // copy row of fr=0 (fi=f0-1)
    const int t0   = tb * NT;
    const int base_t = t0 * STRIDE + (PAD_IN - PW);

    // ---- stage: branch-free global_load_lds, linear LDS dest
    {
        const char* inB = (const char*)inC;
        #pragma unroll
        for (int k = 0; k < KPT; ++k) {
            int s  = tid + k * 256;
            int fr = s / SLR;
            int s2 = s - fr * SLR;
            __builtin_amdgcn_global_load_lds(
                (const __attribute__((address_space(1))) void*)
                    (inB + ((size_t)(brow + fr) * TpadIn + base_t) * 64 + (size_t)s2 * 16),
                (__attribute__((address_space(3))) void*)
                    (ldsb + (k * 256 + (tid & 192)) * 16),
                16, 0, 0);
        }
    }

    // swizzled LDS read bases
    const int tln = lane & 31;
    const int hi  = lane >> 5;
    int baddr0[KW];
    #pragma unroll
    for (int kw = 0; kw < KW; ++kw) {
        int trow = tln * STRIDE + kw;
        int x = trow + TOFF;
        int swz = (((x >> 1) & 3) << 4) | (((x >> 3) & 1) << 6);
        baddr0[kw] = (trow * 64 + hi * 16) ^ swz;
    }

    float bs[16];
    #pragma unroll
    for (int rr = 0; rr < 16; ++rr) bs[rr] = bias[4 * hi + 8 * (rr >> 2) + (rr & 3)];

    __syncthreads();   // drains vmcnt(0): staged tile ready

    f32x16 acc[2];
    #pragma unroll
    for (int nf = 0; nf < 2; ++nf)
        #pragma unroll
        for (int rr = 0; rr < 16; ++rr) acc[nf][rr] = 0.f;

    const char* lrow = ldsb + wave * ROWB;
    #pragma unroll
    for (int df = 0; df < 3; ++df) {
        f16x8 a[KW * 2];
        #pragma unroll
        for (int kw = 0; kw < KW; ++kw)
            #pragma unroll
            for (int ch = 0; ch < 2; ++ch)
                a[kw * 2 + ch] = *reinterpret_cast<const f16x8*>(
                    Ap + (((df * KW + kw) * 2 + ch) << 9) + lane * 8);
        #pragma unroll
        for (int kw = 0; kw < KW; ++kw)
            #pragma unroll
            for (int ch = 0; ch < 2; ++ch)
                #pragma unroll
                for (int nf = 0; nf < 2; ++nf) {
                    f16x8 bf = *reinterpret_cast<const f16x8*>(
                        lrow + ((baddr0[kw] ^ (ch << 5)) + df * ROWB + nf * NFOFF));
                    acc[nf] = __builtin_amdgcn_mfma_f32_32x32x16_f16(a[kw * 2 + ch], bf, acc[nf], 0, 0, 0);
                }
    }

    // ---------------- epilogue ----------------
    const int f = f0 + wave;
    if (f >= NBINS) return;

    char* crow = nullptr;
    if constexpr (PAD_OUT > 0)
        crow = (char*)outC + ((size_t)(b * FROWS + f + 1)) * TpadOut * 64;

    #pragma unroll
    for (int nf = 0; nf < 2; ++nf) {
        int t = t0 + nf * 32 + tln;
        bool vt = (t < Tout);
        float vals[16];
        #pragma unroll
        for (int rr = 0; rr < 16; ++rr) {
            float v = acc[nf][rr] + bs[rr];
            if (DO_LRELU) v = (v > 0.f) ? v : 0.1f * v;
            vals[rr] = v;
        }
        if (vt) {
            #pragma unroll
            for (int rr = 0; rr < 16; ++rr) {
                int o = 4 * hi + 8 * (rr >> 2) + (rr & 3);
                out[(((size_t)b * 32 + o) * NBINS + f) * Tout + t] = vals[rr];
            }
        }
        if constexpr (PAD_OUT > 0) {
            int tg = t + PAD_OUT;
            int swz = (((tg >> 1) & 3) << 4) | (((tg >> 3) & 1) << 6);
            int rowbyte = (tg * 64) ^ swz;
            #pragma unroll
            for (int qq = 0; qq < 4; ++qq) {
                f16x4 hv;
                #pragma unroll
                for (int rr = 0; rr < 4; ++rr)
                    hv[rr] = vt ? (f16)vals[4 * qq + rr] : (f16)0.f;
                *reinterpret_cast<f16x4*>(crow + (rowbyte ^ ((4 * hi + 8 * qq) << 1))) = hv;
            }
        }
    }
    if constexpr (PAD_OUT > 0) {
        if (tb == 0 && lane < PAD_OUT * 4) {   // left pad zeros
            int tgp = lane >> 2, oct = lane & 3;
            f16x8 z;
            #pragma unroll
            for (int j = 0; j < 8; ++j) z[j] = (f16)0.f;
            *reinterpret_cast<f16x8*>(crow + tgp * 64 + oct * 16) = z;
        }
    }
}

// ------------------------------------------------------------ final conv ----
__global__ __launch_bounds__(256) void convo_kernel(const float* __restrict__ in,
                                                    const float* __restrict__ wn,
                                                    const float* __restrict__ bias,
                                                    float* __restrict__ f5,
                                                    float* __restrict__ flat)
{
    int idx = blockIdx.x * 256 + threadIdx.x;
    if (idx >= 4 * NBINS * 101) return;
    int t = idx % 101;
    int rem = idx / 101;
    int f = rem % NBINS;
    int b = rem / NBINS;

    float a = bias[0];
    const float* inb = in + (size_t)b * 32 * NBINS * 101;
    for (int c = 0; c < 32; ++c) {
        #pragma unroll
        for (int df = 0; df < 3; ++df) {
            int fi = f + df - 1;
            if (fi < 0 || fi >= NBINS) continue;
            #pragma unroll
            for (int kw = 0; kw < 3; ++kw) {
                int ti = t + kw - 1;
                if (ti < 0 || ti >= 101) continue;
                a = fmaf(inb[((size_t)c * NBINS + fi) * 101 + ti], wn[(c * 3 + df) * 3 + kw], a);
            }
        }
    }
    f5[idx] = a;
    flat[idx] = a;
}

// ------------------------------------------------------------------ launch --
extern "C" void kernel_launch(void* const* d_in, const int* in_sizes, int n_in,
                              void* d_out, int out_size, void* d_ws, size_t ws_size,
                              hipStream_t stream)
{
    const float* y  = (const float*)d_in[0];
    const float* v0 = (const float*)d_in[1];
    const float* g0 = (const float*)d_in[2];
    const float* b0 = (const float*)d_in[3];
    const float* v1 = (const float*)d_in[4];
    const float* g1 = (const float*)d_in[5];
    const float* b1 = (const float*)d_in[6];
    const float* v2 = (const float*)d_in[7];
    const float* g2 = (const float*)d_in[8];
    const float* b2 = (const float*)d_in[9];
    const float* v3 = (const float*)d_in[10];
    const float* g3 = (const float*)d_in[11];
    const float* b3 = (const float*)d_in[12];
    const float* v4 = (const float*)d_in[13];
    const float* g4 = (const float*)d_in[14];
    const float* b4 = (const float*)d_in[15];
    const float* vo = (const float*)d_in[16];
    const float* go = (const float*)d_in[17];
    const float* bo = (const float*)d_in[18];

    float* out = (float*)d_out;
    float* ws  = (float*)d_ws;

    const size_t SFLAT = (size_t)4 * NBINS * 101;
    const size_t NF0   = (size_t)4 * 32 * NBINS * 801;
    const size_t NF1   = (size_t)4 * 32 * NBINS * 401;
    const size_t NF2   = (size_t)4 * 32 * NBINS * 201;
    const size_t NF3   = (size_t)4 * 32 * NBINS * 101;
    float* oflat = out;
    float* f0 = out + SFLAT;
    float* f1 = f0 + NF0;
    float* f2 = f1 + NF1;
    float* f3 = f2 + NF2;
    float* f4 = f3 + NF3;
    float* f5 = f4 + NF3;

    // mag stashed in (not-yet-written) fmap1 region; consumed before conv1 writes it
    float* mag = f1;

    // ws layout: fp32 small weights, fp16 A-packs, fp16 activation copies
    const int TP0 = 840, TP1 = 456, TP2 = 264, TP3 = 136;
    size_t off = 0;
    float* w0n = ws + off; off += 1568;
    float* won = ws + off; off += 288;
    f16* A1 = (f16*)(ws + off);
    f16* A2 = A1 + 27648;
    f16* A3 = A2 + 27648;
    f16* A4 = A3 + 27648;               // 9216 elements
    f16* f0c = A4 + 9216;               // [4][515][840][32]
    f16* f1c = f0c + (size_t)4 * FROWS * TP0 * 32;   // [4][515][456][32]
    f16* f2c = f1c + (size_t)4 * FROWS * TP1 * 32;   // [4][515][264][32]
    f16* f3c = f2c + (size_t)4 * FROWS * TP2 * 32;   // [4][515][136][32]

    zero_pads<<<dim3(256, 4), 256, 0, stream>>>(f0c, f1c, f2c, f3c);

    prep_kernel<<<161, 256, 0, stream>>>(v0, g0, v1, g1, v2, g2, v3, g3,
                                         v4, g4, vo, go, w0n, won,
                                         A1, A2, A3, A4);

    stft_kernel<<<dim3(NFRAMES, 4), 512, 0, stream>>>(y, mag);

    double sh4 = -(1000.0 * log(0.001 * (5.0 / 7.0)) - 1000.0 * log(0.001)); // 336.472...
    double sh5 = -(1000.0 * log(0.001 * (6.0 / 7.0)) - 1000.0 * log(0.001)); // 154.150...
    float fr4 = (float)(sh4 - floor(sh4));
    float fr5 = (float)(sh5 - floor(sh5));

    harmonic_kernel<<<dim3(NBINS, 4), 256, 0, stream>>>(mag, w0n, b0, f0, f0c, fr4, fr5);

    // conv chain: one-shot gload_lds-staged, fp16-copy in, fp32 fmap out (+ copy)
    conv_v6<9, 2, 4, 4, 4, 7, true><<<7 * 129 * 4, 256, 0, stream>>>(f0c, A1, b1, f1, f1c, 401, TP0, TP1);
    conv_v6<9, 2, 4, 4, 4, 4, true><<<4 * 129 * 4, 256, 0, stream>>>(f1c, A2, b2, f2, f2c, 201, TP1, TP2);
    conv_v6<9, 2, 4, 4, 5, 2, true><<<2 * 129 * 4, 256, 0, stream>>>(f2c, A3, b3, f3, f3c, 101, TP2, TP3);
    conv_v6<3, 1, 1, 5, 0, 2, true><<<2 * 129 * 4, 256, 0, stream>>>(f3c, A4, b4, f4, nullptr, 101, TP3, 0);

    convo_kernel<<<(int)((4 * NBINS * 101 + 255) / 256), 256, 0, stream>>>(f4, won, bo, f5, oflat);
}

// Round 12
// 401.381 us; speedup vs baseline: 2.4303x; 1.0684x over previous
//
#include <hip/hip_runtime.h>
#include <math.h>

#define T_SAMPLES 96000
#define NFRAMES 801
#define NBINS 513
#define FROWS 515   // NBINS + 2 guard rows (index f+1; rows 0 and 514 are zero)
#define EPS32 1.1920928955078125e-07f

typedef _Float16 f16;
typedef f16 f16x2 __attribute__((ext_vector_type(2)));
typedef f16 f16x4 __attribute__((ext_vector_type(4)));
typedef f16 f16x8 __attribute__((ext_vector_type(8)));
typedef float f32x4 __attribute__((ext_vector_type(4)));
typedef float f32x16 __attribute__((ext_vector_type(16)));

// ---------------------------------------------------------------- STFT ----
__global__ __launch_bounds__(512) void stft_kernel(const float* __restrict__ y,
                                                   float* __restrict__ mag)
{
    int t = blockIdx.x;   // frame 0..800
    int b = blockIdx.y;   // batch 0..3
    int tid = threadIdx.x;

    __shared__ float2 buf[2][1024];

    const float* yb = y + (size_t)b * T_SAMPLES;
    for (int n = tid; n < 1024; n += 512) {
        int j = t * 120 + n - 512;          // reflect pad 512 both sides
        if (j < 0) j = -j;
        if (j >= T_SAMPLES) j = 2 * T_SAMPLES - 2 - j;
        float v = yb[j];
        int np_ = n - 212;                  // window placed at lp=212, len 600
        float w = 0.0f;
        if (np_ >= 0 && np_ < 600)
            w = 0.5f * (1.0f - cospif((float)np_ * (1.0f / 300.0f)));
        buf[0][n] = make_float2(v * w, 0.0f);
    }
    __syncthreads();

    int srcb = 0;
    #pragma unroll
    for (int stage = 0; stage < 10; ++stage) {
        int m  = 1 << stage;
        int jm = (tid >> stage) << stage;   // j*m
        float jf = (float)jm * (1.0f / 512.0f);
        float wr = cospif(jf);
        float wi = -sinpif(jf);             // e^{-i pi j/l}
        float2 a  = buf[srcb][tid];
        float2 bb = buf[srcb][tid + 512];
        float2 s  = make_float2(a.x + bb.x, a.y + bb.y);
        float2 d  = make_float2(a.x - bb.x, a.y - bb.y);
        float2 dw = make_float2(d.x * wr - d.y * wi, d.x * wi + d.y * wr);
        buf[srcb ^ 1][tid + jm]     = s;
        buf[srcb ^ 1][tid + jm + m] = dw;
        __syncthreads();
        srcb ^= 1;
    }

    float2 v = buf[srcb][tid];
    float msq = v.x * v.x + v.y * v.y;
    mag[((size_t)b * NBINS + tid) * NFRAMES + t] = sqrtf(fmaxf(msq, EPS32));
    if (tid == 0) {
        float2 v5 = buf[srcb][512];
        float m5 = v5.x * v5.x + v5.y * v5.y;
        mag[((size_t)b * NBINS + 512) * NFRAMES + t] = sqrtf(fmaxf(m5, EPS32));
    }
}

// -------------------------------------- fused weight prep + pad zeroing ----
// Blocks 0..160: weight-norm + A-pack (as before).
// Blocks 161..416: zero guard rows / tail cols of all 5 fp16 copies.
__global__ __launch_bounds__(256) void prep_kernel(
    const float* __restrict__ v0, const float* __restrict__ g0,
    const float* __restrict__ v1, const float* __restrict__ g1,
    const float* __restrict__ v2, const float* __restrict__ g2,
    const float* __restrict__ v3, const float* __restrict__ g3,
    const float* __restrict__ v4, const float* __restrict__ g4,
    const float* __restrict__ vo, const float* __restrict__ go,
    float* __restrict__ w0n, float* __restrict__ won,
    f16* __restrict__ A1, f16* __restrict__ A2,
    f16* __restrict__ A3, f16* __restrict__ A4,
    f16* __restrict__ f0c, f16* __restrict__ f1c, f16* __restrict__ f2c,
    f16* __restrict__ f3c, f16* __restrict__ f4c)
{
    int blk = blockIdx.x;
    int tid = threadIdx.x;

    if (blk >= 161) {                       // ---- pad zeroing part
        int zb = blk - 161;                 // 0..255
        const int TPs[5]   = {840, 456, 264, 136, 136};
        const int tails[5] = {840, 420, 228, 133, 136};
        f16* ptrs[5] = {f0c, f1c, f2c, f3c, f4c};
        f16x8 z;
        #pragma unroll
        for (int j = 0; j < 8; ++j) z[j] = (f16)0.f;
        for (int l = 0; l < 5; ++l) {
            f16* p = ptrs[l];
            int TP = TPs[l], tail = tails[l];
            int rowSlots   = TP * 4;
            int guardSlots = 8 * rowSlots;
            int tailCols   = TP - tail;
            int tailSlots  = 4 * FROWS * tailCols * 4;
            int total = guardSlots + tailSlots;
            for (int i = zb * 256 + tid; i < total; i += 256 * 256) {
                size_t slot;
                if (i < guardSlots) {
                    int rs = i / rowSlots;
                    int q  = i - rs * rowSlots;
                    int b  = rs >> 1;
                    int r  = (rs & 1) ? (FROWS - 1) : 0;
                    slot = ((size_t)(b * FROWS + r)) * rowSlots + q;
                } else {
                    int j2 = i - guardSlots;
                    int per = tailCols * 4;
                    int row = j2 / per;
                    int q   = j2 - row * per;
                    slot = ((size_t)row * TP + tail) * 4 + q;
                }
                *reinterpret_cast<f16x8*>((char*)p + slot * 16) = z;
            }
        }
        return;
    }

    const float *v, *g; f16* Ap = nullptr; float* outf = nullptr;
    int o, per_o, KW = 9;
    if (blk < 32)        { v = v1; g = g1; Ap = A1; o = blk;       per_o = 864; }
    else if (blk < 64)   { v = v2; g = g2; Ap = A2; o = blk - 32;  per_o = 864; }
    else if (blk < 96)   { v = v3; g = g3; Ap = A3; o = blk - 64;  per_o = 864; }
    else if (blk < 128)  { v = v4; g = g4; Ap = A4; o = blk - 96;  per_o = 288; KW = 3; }
    else if (blk < 160)  { v = v0; g = g0; outf = w0n; o = blk - 128; per_o = 49; }
    else                 { v = vo; g = go; outf = won; o = 0;        per_o = 288; }

    const float* vv = v + (size_t)o * per_o;
    __shared__ float red[256];
    float s = 0.f;
    for (int i = tid; i < per_o; i += 256) { float x = vv[i]; s = fmaf(x, x, s); }
    red[tid] = s;
    __syncthreads();
    for (int k = 128; k > 0; k >>= 1) {
        if (tid < k) red[tid] += red[tid + k];
        __syncthreads();
    }
    float scale = g[o] / sqrtf(red[0]);

    if (outf) {
        for (int i = tid; i < per_o; i += 256)
            outf[(size_t)o * per_o + i] = vv[i] * scale;
    } else {
        for (int i = tid; i < per_o; i += 256) {
            int tap = i >> 5;
            int c   = i & 31;
            int df  = tap / KW, kw = tap - df * KW;
            float val = vv[(c * 3 + df) * KW + kw] * scale;
            int l = ((c >> 3) & 1) * 32 + o;
            int ch = c >> 4;
            int j = c & 7;
            Ap[(((tap * 2 + ch) * 64 + l) << 3) + j] = (f16)val;
        }
    }
}

// -------------------------------------------------------- harmonic conv ----
__global__ __launch_bounds__(256) void harmonic_kernel(const float* __restrict__ mag,
                                                       const float* __restrict__ wn,
                                                       const float* __restrict__ bias,
                                                       float* __restrict__ out,
                                                       f16* __restrict__ f0c,
                                                       float fr4, float fr5)
{
    int f = blockIdx.x;
    int b = blockIdx.y;
    int tid = threadIdx.x;

    __shared__ float rows[3][808];

    const float* mb = mag + (size_t)b * NBINS * NFRAMES;

    for (int i = tid; i < 808; i += 256) {
        int tt = i - 3;
        bool ok = (tt >= 0) && (tt < NFRAMES);
        float m336 = (ok && f >= 336) ? mb[(size_t)(f - 336) * NFRAMES + tt] : 0.f;
        float m337 = (ok && f >= 337) ? mb[(size_t)(f - 337) * NFRAMES + tt] : 0.f;
        float m154 = (ok && f >= 154) ? mb[(size_t)(f - 154) * NFRAMES + tt] : 0.f;
        float m155 = (ok && f >= 155) ? mb[(size_t)(f - 155) * NFRAMES + tt] : 0.f;
        float m0   = ok ? mb[(size_t)f * NFRAMES + tt] : 0.f;
        rows[0][i] = (1.f - fr4) * m336 + fr4 * m337;
        rows[1][i] = (1.f - fr5) * m154 + fr5 * m155;
        rows[2][i] = m0;
    }
    __syncthreads();

    char* crow = (char*)f0c + ((size_t)(b * FROWS + f + 1)) * 840 * 64;

    // left pad zeros: tg in [0,4)
    if (tid < 16) {
        int tg = tid >> 2, q = tid & 3;
        int swz = (((tg >> 1) & 3) << 4) | (((tg >> 3) & 1) << 6);
        f16x8 z;
        #pragma unroll
        for (int j = 0; j < 8; ++j) z[j] = (f16)0.f;
        *reinterpret_cast<f16x8*>(crow + ((tg * 64 + q * 16) ^ swz)) = z;
    }

    #pragma unroll
    for (int chunk = 0; chunk < 4; ++chunk) {
        int t = chunk * 256 + tid;
        if (t < NFRAMES) {
            float win[3][7];
            #pragma unroll
            for (int r = 0; r < 3; ++r)
                #pragma unroll
                for (int k = 0; k < 7; ++k)
                    win[r][k] = rows[r][t + k];

            float vals[32];
            #pragma unroll
            for (int o = 0; o < 32; ++o) {
                float a = bias[o];
                #pragma unroll
                for (int r = 0; r < 3; ++r) {
                    const float* wr = wn + (o * 7 + 4 + r) * 7;
                    #pragma unroll
                    for (int kw = 0; kw < 7; ++kw)
                        a = fmaf(win[r][kw], wr[kw], a);
                }
                vals[o] = (a > 0.f) ? a : 0.1f * a;
            }

            #pragma unroll
            for (int o = 0; o < 32; ++o)
                out[(((size_t)b * 32 + o) * NBINS + f) * (size_t)NFRAMES + t] = vals[o];

            int tg = t + 4;
            int swz = (((tg >> 1) & 3) << 4) | (((tg >> 3) & 1) << 6);
            #pragma unroll
            for (int q = 0; q < 4; ++q) {
                f16x8 h;
                #pragma unroll
                for (int j = 0; j < 8; ++j) h[j] = (f16)vals[q * 8 + j];
                *reinterpret_cast<f16x8*>(crow + ((tg * 64 + q * 16) ^ swz)) = h;
            }
        } else if (t < 836) {                 // right pad zeros: tg in [805,840)
            int tg = t + 4;
            int swz = (((tg >> 1) & 3) << 4) | (((tg >> 3) & 1) << 6);
            f16x8 z;
            #pragma unroll
            for (int j = 0; j < 8; ++j) z[j] = (f16)0.f;
            #pragma unroll
            for (int q = 0; q < 4; ++q)
                *reinterpret_cast<f16x8*>(crow + ((tg * 64 + q * 16) ^ swz)) = z;
        }
    }
}

// ------------------------------------------------ one-shot MFMA conv v6 ----
// One tile per block, full-grid TLP; stage via global_load_lds (zero staging
// VGPRs); m204 bijective XCD swizzle with tb-fastest work order.
template<int KW, int STRIDE, int PW, int PAD_IN, int PAD_OUT, int NTB, int MINW, bool DO_LRELU>
__global__ __launch_bounds__(256, MINW) void conv_v6(
    const f16* __restrict__ inC, const f16* __restrict__ Ap,
    const float* __restrict__ bias, float* __restrict__ out,
    f16* __restrict__ outC, int Tout, int TpadIn, int TpadOut)
{
    constexpr int NT    = 64;
    constexpr int TR    = NT * STRIDE + KW - 1;
    constexpr int TRP   = (TR + 1) & ~1;
    constexpr int ROWB  = TRP * 64;
    constexpr int SLR   = TRP * 4;             // 16B slots per f-row
    constexpr int SL    = 6 * SLR;             // active slots
    constexpr int KPT   = (SL + 255) / 256;    // issue groups (unconditional)
    constexpr int TOFF  = (PAD_IN - PW) & 15;
    constexpr int NFOFF = 32 * STRIDE * 64;

    __shared__ char ldsb[KPT * 256 * 16];      // padded: slack absorbs tail group

    const int tid  = threadIdx.x;
    const int lane = tid & 63;
    const int wave = tid >> 6;

    // bijective XCD swizzle (m204), work order: tb fastest, then fblk, then b
    const int NWG = NTB * 129 * 4;
    int lin = blockIdx.x;
    int xcd = lin & 7, sl = lin >> 3;
    const int q = NWG / 8, r = NWG % 8;
    int work = (xcd < r ? xcd * (q + 1) : r * (q + 1) + (xcd - r) * q) + sl;
    const int tb   = work % NTB;
    int rem        = work / NTB;
    const int fblk = rem % 129;
    const int b    = rem / 129;
    const int f0   = fblk * 4;
    const int brow = b * FROWS + f0;           // copy row of fr=0 (fi=f0-1)
    const int t0   = tb * NT;
    const int base_t = t0 * STRIDE + (PAD_IN - PW);

    // ---- stage: branch-free global_load_lds, linear LDS dest
    {
        const char* inB = (const char*)inC;
        #pragma unroll
        for (int k = 0; k < KPT; ++k) {
            int s  = tid + k * 256;
            int fr = s / SLR;
            int s2 = s - fr * SLR;
            __builtin_amdgcn_global_load_lds(
                (const __attribute__((address_space(1))) void*)
                    (inB + ((size_t)(brow + fr) * TpadIn + base_t) * 64 + (size_t)s2 * 16),
                (__attribute__((address_space(3))) void*)
                    (ldsb + (k * 256 + (tid & 192)) * 16),
                16, 0, 0);
        }
    }

    // swizzled LDS read bases
    const int tln = lane & 31;
    const int hi  = lane >> 5;
    int baddr0[KW];
    #pragma unroll
    for (int kw = 0; kw < KW; ++kw) {
        int trow = tln * STRIDE + kw;
        int x = trow + TOFF;
        int swz = (((x >> 1) & 3) << 4) | (((x >> 3) & 1) << 6);
        baddr0[kw] = (trow * 64 + hi * 16) ^ swz;
    }

    float bs[16];
    #pragma unroll
    for (int rr = 0; rr < 16; ++rr) bs[rr] = bias[4 * hi + 8 * (rr >> 2) + (rr & 3)];

    __syncthreads();   // drains vmcnt(0): staged tile ready

    f32x16 acc[2];
    #pragma unroll
    for (int nf = 0; nf < 2; ++nf)
        #pragma unroll
        for (int rr = 0; rr < 16; ++rr) acc[nf][rr] = 0.f;

    const char* lrow = ldsb + wave * ROWB;
    #pragma unroll
    for (int df = 0; df < 3; ++df) {
        f16x8 a[KW * 2];
        #pragma unroll
        for (int kw = 0; kw < KW; ++kw)
            #pragma unroll
            for (int ch = 0; ch < 2; ++ch)
                a[kw * 2 + ch] = *reinterpret_cast<const f16x8*>(
                    Ap + (((df * KW + kw) * 2 + ch) << 9) + lane * 8);
        #pragma unroll
        for (int kw = 0; kw < KW; ++kw)
            #pragma unroll
            for (int ch = 0; ch < 2; ++ch)
                #pragma unroll
                for (int nf = 0; nf < 2; ++nf) {
                    f16x8 bf = *reinterpret_cast<const f16x8*>(
                        lrow + ((baddr0[kw] ^ (ch << 5)) + df * ROWB + nf * NFOFF));
                    acc[nf] = __builtin_amdgcn_mfma_f32_32x32x16_f16(a[kw * 2 + ch], bf, acc[nf], 0, 0, 0);
                }
    }

    // ---------------- epilogue ----------------
    const int f = f0 + wave;
    if (f >= NBINS) return;

    char* crow = nullptr;
    if constexpr (PAD_OUT > 0)
        crow = (char*)outC + ((size_t)(b * FROWS + f + 1)) * TpadOut * 64;

    #pragma unroll
    for (int nf = 0; nf < 2; ++nf) {
        int t = t0 + nf * 32 + tln;
        bool vt = (t < Tout);
        float vals[16];
        #pragma unroll
        for (int rr = 0; rr < 16; ++rr) {
            float v = acc[nf][rr] + bs[rr];
            if (DO_LRELU) v = (v > 0.f) ? v : 0.1f * v;
            vals[rr] = v;
        }
        if (vt) {
            #pragma unroll
            for (int rr = 0; rr < 16; ++rr) {
                int o = 4 * hi + 8 * (rr >> 2) + (rr & 3);
                out[(((size_t)b * 32 + o) * NBINS + f) * Tout + t] = vals[rr];
            }
        }
        if constexpr (PAD_OUT > 0) {
            int tg = t + PAD_OUT;
            int swz = (((tg >> 1) & 3) << 4) | (((tg >> 3) & 1) << 6);
            int rowbyte = (tg * 64) ^ swz;
            #pragma unroll
            for (int qq = 0; qq < 4; ++qq) {
                f16x4 hv;
                #pragma unroll
                for (int rr = 0; rr < 4; ++rr)
                    hv[rr] = vt ? (f16)vals[4 * qq + rr] : (f16)0.f;
                *reinterpret_cast<f16x4*>(crow + (rowbyte ^ ((4 * hi + 8 * qq) << 1))) = hv;
            }
        }
    }
    if constexpr (PAD_OUT > 0) {
        if (tb == 0 && lane < PAD_OUT * 4) {   // left pad zeros
            int tgp = lane >> 2, oct = lane & 3;
            f16x8 z;
            #pragma unroll
            for (int j = 0; j < 8; ++j) z[j] = (f16)0.f;
            *reinterpret_cast<f16x8*>(crow + tgp * 64 + oct * 16) = z;
        }
    }
}

// ------------------------------------------------------- final conv v2 ----
// Reads the f4c fp16 baked-swizzle copy (guard rows -> branch-free f+-1),
// 36 x 16B vector loads per thread. Block = 2 f-rows x 128 t-lanes.
__global__ __launch_bounds__(256) void convo_v2(const f16* __restrict__ inC,
                                                const float* __restrict__ won,
                                                const float* __restrict__ bias,
                                                float* __restrict__ f5,
                                                float* __restrict__ flat)
{
    const int TP4 = 136;
    int blk = blockIdx.x;                  // (b, fpair)
    int b = blk / 257, fp = blk - (b * 257);
    int tid = threadIdx.x;
    int f = fp * 2 + (tid >> 7);
    int t = tid & 127;
    if (f >= NBINS || t >= 101) return;

    float acc = bias[0];
    #pragma unroll
    for (int df = 0; df < 3; ++df) {
        const char* row = (const char*)inC + ((size_t)(b * FROWS + f + df)) * TP4 * 64;
        #pragma unroll
        for (int kw = 0; kw < 3; ++kw) {
            int tg = t + kw;               // (t + kw - 1) + PAD_OUT(1)
            int swz = (((tg >> 1) & 3) << 4) | (((tg >> 3) & 1) << 6);
            #pragma unroll
            for (int q2 = 0; q2 < 4; ++q2) {
                f16x8 h = *reinterpret_cast<const f16x8*>(row + ((tg * 64 + q2 * 16) ^ swz));
                #pragma unroll
                for (int j = 0; j < 8; ++j)
                    acc = fmaf((float)h[j], won[((q2 * 8 + j) * 3 + df) * 3 + kw], acc);
            }
        }
    }
    size_t idx = ((size_t)(b * NBINS + f)) * 101 + t;
    f5[idx] = acc;
    flat[idx] = acc;
}

// ------------------------------------------------------------------ launch --
extern "C" void kernel_launch(void* const* d_in, const int* in_sizes, int n_in,
                              void* d_out, int out_size, void* d_ws, size_t ws_size,
                              hipStream_t stream)
{
    const float* y  = (const float*)d_in[0];
    const float* v0 = (const float*)d_in[1];
    const float* g0 = (const float*)d_in[2];
    const float* b0 = (const float*)d_in[3];
    const float* v1 = (const float*)d_in[4];
    const float* g1 = (const float*)d_in[5];
    const float* b1 = (const float*)d_in[6];
    const float* v2 = (const float*)d_in[7];
    const float* g2 = (const float*)d_in[8];
    const float* b2 = (const float*)d_in[9];
    const float* v3 = (const float*)d_in[10];
    const float* g3 = (const float*)d_in[11];
    const float* b3 = (const float*)d_in[12];
    const float* v4 = (const float*)d_in[13];
    const float* g4 = (const float*)d_in[14];
    const float* b4 = (const float*)d_in[15];
    const float* vo = (const float*)d_in[16];
    const float* go = (const float*)d_in[17];
    const float* bo = (const float*)d_in[18];

    float* out = (float*)d_out;
    float* ws  = (float*)d_ws;

    const size_t SFLAT = (size_t)4 * NBINS * 101;
    const size_t NF0   = (size_t)4 * 32 * NBINS * 801;
    const size_t NF1   = (size_t)4 * 32 * NBINS * 401;
    const size_t NF2   = (size_t)4 * 32 * NBINS * 201;
    const size_t NF3   = (size_t)4 * 32 * NBINS * 101;
    float* oflat = out;
    float* f0 = out + SFLAT;
    float* f1 = f0 + NF0;
    float* f2 = f1 + NF1;
    float* f3 = f2 + NF2;
    float* f4 = f3 + NF3;
    float* f5 = f4 + NF3;

    // mag stashed in (not-yet-written) fmap1 region; consumed before conv1 writes it
    float* mag = f1;

    // ws layout: fp32 small weights, fp16 A-packs, fp16 activation copies
    const int TP0 = 840, TP1 = 456, TP2 = 264, TP3 = 136, TP4 = 136;
    size_t off = 0;
    float* w0n = ws + off; off += 1568;
    float* won = ws + off; off += 288;
    f16* A1 = (f16*)(ws + off);
    f16* A2 = A1 + 27648;
    f16* A3 = A2 + 27648;
    f16* A4 = A3 + 27648;               // 9216 elements
    f16* f0c = A4 + 9216;               // [4][515][840][32]
    f16* f1c = f0c + (size_t)4 * FROWS * TP0 * 32;   // [4][515][456][32]
    f16* f2c = f1c + (size_t)4 * FROWS * TP1 * 32;   // [4][515][264][32]
    f16* f3c = f2c + (size_t)4 * FROWS * TP2 * 32;   // [4][515][136][32]
    f16* f4c = f3c + (size_t)4 * FROWS * TP3 * 32;   // [4][515][136][32]

    prep_kernel<<<417, 256, 0, stream>>>(v0, g0, v1, g1, v2, g2, v3, g3,
                                         v4, g4, vo, go, w0n, won,
                                         A1, A2, A3, A4,
                                         f0c, f1c, f2c, f3c, f4c);

    stft_kernel<<<dim3(NFRAMES, 4), 512, 0, stream>>>(y, mag);

    double sh4 = -(1000.0 * log(0.001 * (5.0 / 7.0)) - 1000.0 * log(0.001)); // 336.472...
    double sh5 = -(1000.0 * log(0.001 * (6.0 / 7.0)) - 1000.0 * log(0.001)); // 154.150...
    float fr4 = (float)(sh4 - floor(sh4));
    float fr5 = (float)(sh5 - floor(sh5));

    harmonic_kernel<<<dim3(NBINS, 4), 256, 0, stream>>>(mag, w0n, b0, f0, f0c, fr4, fr5);

    // conv chain: one-shot gload_lds-staged, fp16-copy in, fp32 fmap out (+ copy)
    conv_v6<9, 2, 4, 4, 4, 7, 3, true><<<7 * 129 * 4, 256, 0, stream>>>(f0c, A1, b1, f1, f1c, 401, TP0, TP1);
    conv_v6<9, 2, 4, 4, 4, 4, 3, true><<<4 * 129 * 4, 256, 0, stream>>>(f1c, A2, b2, f2, f2c, 201, TP1, TP2);
    conv_v6<9, 2, 4, 4, 5, 2, 3, true><<<2 * 129 * 4, 256, 0, stream>>>(f2c, A3, b3, f3, f3c, 101, TP2, TP3);
    conv_v6<3, 1, 1, 5, 1, 2, 4, true><<<2 * 129 * 4, 256, 0, stream>>>(f3c, A4, b4, f4, f4c, 101, TP3, TP4);

    convo_v2<<<257 * 4, 256, 0, stream>>>(f4c, won, bo, f5, oflat);
}

// Round 13
// 392.556 us; speedup vs baseline: 2.4849x; 1.0225x over previous
//
#include <hip/hip_runtime.h>
#include <math.h>

#define T_SAMPLES 96000
#define NFRAMES 801
#define NBINS 513
#define FROWS 515   // NBINS + 2 guard rows (index f+1; rows 0 and 514 are zero)
#define MAGT 804    // mag row stride (floats): 16B-aligned rows for float4 stores
#define EPS32 1.1920928955078125e-07f

typedef _Float16 f16;
typedef f16 f16x2 __attribute__((ext_vector_type(2)));
typedef f16 f16x4 __attribute__((ext_vector_type(4)));
typedef f16 f16x8 __attribute__((ext_vector_type(8)));
typedef float f32x4 __attribute__((ext_vector_type(4)));
typedef float f32x16 __attribute__((ext_vector_type(16)));

// -------------------------------------------------------------- STFT v2 ----
// 256 threads = 4 waves; each wave FFTs a PAIR of frames packed as complex
// z = x1 + i*x2 (one 1024-pt Stockham per 2 frames). Unpack:
//   X1(k) = (Z(k)+conj(Z(N-k)))/2,  X2(k) = -i(Z(k)-conj(Z(N-k)))/2.
// Mags staged in LDS (overlay of the free ping half), then written as two
// aligned float4 per (f, 8-frame block) -> sector-aligned coalesced stores.
__global__ __launch_bounds__(256) void stft_v2(const float* __restrict__ y,
                                               float* __restrict__ mag)
{
    __shared__ float2 fft[2][4][1024];           // 64 KB; results end in fft[0]
    float* mg = (float*)&fft[1][0][0];           // [8][520] overlay (16.6 KB)
    const int MGS = 520;

    const int tid  = threadIdx.x;
    const int lane = tid & 63;
    const int wv   = tid >> 6;
    const int t0   = blockIdx.x * 8;
    const int b    = blockIdx.y;
    const float* yb = y + (size_t)b * T_SAMPLES;

    // ---- load + window two frames, packed
    const int tA = t0 + 2 * wv;
    for (int n = lane; n < 1024; n += 64) {
        float w = 0.f;
        int np_ = n - 212;
        if (np_ >= 0 && np_ < 600)
            w = 0.5f * (1.0f - cospif((float)np_ * (1.0f / 300.0f)));
        int j1 = tA * 120 + n - 512;
        if (j1 < 0) j1 = -j1;
        if (j1 >= T_SAMPLES) j1 = 2 * T_SAMPLES - 2 - j1;
        int j2 = j1 + 120;                        // (tA+1)*120 + n - 512, pre-reflect
        {
            int jj = tA * 120 + 120 + n - 512;
            if (jj < 0) jj = -jj;
            if (jj >= T_SAMPLES) jj = 2 * T_SAMPLES - 2 - jj;
            j2 = jj;
        }
        fft[0][wv][n] = make_float2(w * yb[j1], w * yb[j2]);
    }
    __syncthreads();

    // ---- 10-stage Stockham (per-wave, ping-pong)
    int srcb = 0;
    #pragma unroll
    for (int stage = 0; stage < 10; ++stage) {
        int m = 1 << stage;
        #pragma unroll
        for (int it = 0; it < 8; ++it) {
            int idx = lane + it * 64;             // 0..511
            int jm  = (idx >> stage) << stage;
            float jf = (float)jm * (1.0f / 512.0f);
            float wr = cospif(jf);
            float wi = -sinpif(jf);
            float2 a  = fft[srcb][wv][idx];
            float2 bb = fft[srcb][wv][idx + 512];
            float2 s  = make_float2(a.x + bb.x, a.y + bb.y);
            float2 d  = make_float2(a.x - bb.x, a.y - bb.y);
            float2 dw = make_float2(d.x * wr - d.y * wi, d.x * wi + d.y * wr);
            fft[srcb ^ 1][wv][idx + jm]     = s;
            fft[srcb ^ 1][wv][idx + jm + m] = dw;
        }
        __syncthreads();
        srcb ^= 1;
    }
    // srcb == 0: results in fft[0]; fft[1] free -> mg overlay

    // ---- unpack + magnitudes into mg[frame][k]
    for (int k = lane; k < 513; k += 64) {
        float2 zk = fft[0][wv][k];
        float2 zr = fft[0][wv][(1024 - k) & 1023];
        float x1r = 0.5f * (zk.x + zr.x);
        float x1i = 0.5f * (zk.y - zr.y);
        float x2r = 0.5f * (zk.y + zr.y);
        float x2i = 0.5f * (zr.x - zk.x);
        mg[(2 * wv)     * MGS + k] = sqrtf(fmaxf(x1r * x1r + x1i * x1i, EPS32));
        mg[(2 * wv + 1) * MGS + k] = sqrtf(fmaxf(x2r * x2r + x2i * x2i, EPS32));
    }
    __syncthreads();

    // ---- transposed coalesced store: mag[b][f][t0..t0+7]
    for (int f = tid; f < 513; f += 256) {
        size_t base = ((size_t)(b * NBINS) + f) * MAGT + t0;
        if (t0 + 7 < NFRAMES) {
            f32x4 v0 = {mg[0 * MGS + f], mg[1 * MGS + f], mg[2 * MGS + f], mg[3 * MGS + f]};
            f32x4 v1 = {mg[4 * MGS + f], mg[5 * MGS + f], mg[6 * MGS + f], mg[7 * MGS + f]};
            *reinterpret_cast<f32x4*>(&mag[base])     = v0;
            *reinterpret_cast<f32x4*>(&mag[base + 4]) = v1;
        } else {
            #pragma unroll
            for (int p = 0; p < 8; ++p)
                if (t0 + p < NFRAMES) mag[base + p] = mg[p * MGS + f];
        }
    }
}

// -------------------------------------- fused weight prep + pad zeroing ----
__global__ __launch_bounds__(256) void prep_kernel(
    const float* __restrict__ v0, const float* __restrict__ g0,
    const float* __restrict__ v1, const float* __restrict__ g1,
    const float* __restrict__ v2, const float* __restrict__ g2,
    const float* __restrict__ v3, const float* __restrict__ g3,
    const float* __restrict__ v4, const float* __restrict__ g4,
    const float* __restrict__ vo, const float* __restrict__ go,
    float* __restrict__ w0n, float* __restrict__ won,
    f16* __restrict__ A1, f16* __restrict__ A2,
    f16* __restrict__ A3, f16* __restrict__ A4,
    f16* __restrict__ f0c, f16* __restrict__ f1c, f16* __restrict__ f2c,
    f16* __restrict__ f3c, f16* __restrict__ f4c)
{
    int blk = blockIdx.x;
    int tid = threadIdx.x;

    if (blk >= 161) {                       // ---- pad zeroing part
        int zb = blk - 161;                 // 0..255
        const int TPs[5]   = {840, 456, 264, 136, 136};
        const int tails[5] = {840, 420, 228, 133, 136};
        f16* ptrs[5] = {f0c, f1c, f2c, f3c, f4c};
        f16x8 z;
        #pragma unroll
        for (int j = 0; j < 8; ++j) z[j] = (f16)0.f;
        for (int l = 0; l < 5; ++l) {
            f16* p = ptrs[l];
            int TP = TPs[l], tail = tails[l];
            int rowSlots   = TP * 4;
            int guardSlots = 8 * rowSlots;
            int tailCols   = TP - tail;
            int tailSlots  = 4 * FROWS * tailCols * 4;
            int total = guardSlots + tailSlots;
            for (int i = zb * 256 + tid; i < total; i += 256 * 256) {
                size_t slot;
                if (i < guardSlots) {
                    int rs = i / rowSlots;
                    int q  = i - rs * rowSlots;
                    int b  = rs >> 1;
                    int r  = (rs & 1) ? (FROWS - 1) : 0;
                    slot = ((size_t)(b * FROWS + r)) * rowSlots + q;
                } else {
                    int j2 = i - guardSlots;
                    int per = tailCols * 4;
                    int row = j2 / per;
                    int q   = j2 - row * per;
                    slot = ((size_t)row * TP + tail) * 4 + q;
                }
                *reinterpret_cast<f16x8*>((char*)p + slot * 16) = z;
            }
        }
        return;
    }

    const float *v, *g; f16* Ap = nullptr; float* outf = nullptr;
    int o, per_o, KW = 9;
    if (blk < 32)        { v = v1; g = g1; Ap = A1; o = blk;       per_o = 864; }
    else if (blk < 64)   { v = v2; g = g2; Ap = A2; o = blk - 32;  per_o = 864; }
    else if (blk < 96)   { v = v3; g = g3; Ap = A3; o = blk - 64;  per_o = 864; }
    else if (blk < 128)  { v = v4; g = g4; Ap = A4; o = blk - 96;  per_o = 288; KW = 3; }
    else if (blk < 160)  { v = v0; g = g0; outf = w0n; o = blk - 128; per_o = 49; }
    else                 { v = vo; g = go; outf = won; o = 0;        per_o = 288; }

    const float* vv = v + (size_t)o * per_o;
    __shared__ float red[256];
    float s = 0.f;
    for (int i = tid; i < per_o; i += 256) { float x = vv[i]; s = fmaf(x, x, s); }
    red[tid] = s;
    __syncthreads();
    for (int k = 128; k > 0; k >>= 1) {
        if (tid < k) red[tid] += red[tid + k];
        __syncthreads();
    }
    float scale = g[o] / sqrtf(red[0]);

    if (outf) {
        for (int i = tid; i < per_o; i += 256)
            outf[(size_t)o * per_o + i] = vv[i] * scale;
    } else {
        for (int i = tid; i < per_o; i += 256) {
            int tap = i >> 5;
            int c   = i & 31;
            int df  = tap / KW, kw = tap - df * KW;
            float val = vv[(c * 3 + df) * KW + kw] * scale;
            int l = ((c >> 3) & 1) * 32 + o;
            int ch = c >> 4;
            int j = c & 7;
            Ap[(((tap * 2 + ch) * 64 + l) << 3) + j] = (f16)val;
        }
    }
}

// -------------------------------------------------------- harmonic conv ----
__global__ __launch_bounds__(256) void harmonic_kernel(const float* __restrict__ mag,
                                                       const float* __restrict__ wn,
                                                       const float* __restrict__ bias,
                                                       float* __restrict__ out,
                                                       f16* __restrict__ f0c,
                                                       float fr4, float fr5)
{
    int f = blockIdx.x;
    int b = blockIdx.y;
    int tid = threadIdx.x;

    __shared__ float rows[3][808];

    const float* mb = mag + (size_t)b * NBINS * MAGT;

    for (int i = tid; i < 808; i += 256) {
        int tt = i - 3;
        bool ok = (tt >= 0) && (tt < NFRAMES);
        float m336 = (ok && f >= 336) ? mb[(size_t)(f - 336) * MAGT + tt] : 0.f;
        float m337 = (ok && f >= 337) ? mb[(size_t)(f - 337) * MAGT + tt] : 0.f;
        float m154 = (ok && f >= 154) ? mb[(size_t)(f - 154) * MAGT + tt] : 0.f;
        float m155 = (ok && f >= 155) ? mb[(size_t)(f - 155) * MAGT + tt] : 0.f;
        float m0   = ok ? mb[(size_t)f * MAGT + tt] : 0.f;
        rows[0][i] = (1.f - fr4) * m336 + fr4 * m337;
        rows[1][i] = (1.f - fr5) * m154 + fr5 * m155;
        rows[2][i] = m0;
    }
    __syncthreads();

    char* crow = (char*)f0c + ((size_t)(b * FROWS + f + 1)) * 840 * 64;

    // left pad zeros: tg in [0,4)
    if (tid < 16) {
        int tg = tid >> 2, q = tid & 3;
        int swz = (((tg >> 1) & 3) << 4) | (((tg >> 3) & 1) << 6);
        f16x8 z;
        #pragma unroll
        for (int j = 0; j < 8; ++j) z[j] = (f16)0.f;
        *reinterpret_cast<f16x8*>(crow + ((tg * 64 + q * 16) ^ swz)) = z;
    }

    #pragma unroll
    for (int chunk = 0; chunk < 4; ++chunk) {
        int t = chunk * 256 + tid;
        if (t < NFRAMES) {
            float win[3][7];
            #pragma unroll
            for (int r = 0; r < 3; ++r)
                #pragma unroll
                for (int k = 0; k < 7; ++k)
                    win[r][k] = rows[r][t + k];

            float vals[32];
            #pragma unroll
            for (int o = 0; o < 32; ++o) {
                float a = bias[o];
                #pragma unroll
                for (int r = 0; r < 3; ++r) {
                    const float* wr = wn + (o * 7 + 4 + r) * 7;
                    #pragma unroll
                    for (int kw = 0; kw < 7; ++kw)
                        a = fmaf(win[r][kw], wr[kw], a);
                }
                vals[o] = (a > 0.f) ? a : 0.1f * a;
            }

            #pragma unroll
            for (int o = 0; o < 32; ++o)
                out[(((size_t)b * 32 + o) * NBINS + f) * (size_t)NFRAMES + t] = vals[o];

            int tg = t + 4;
            int swz = (((tg >> 1) & 3) << 4) | (((tg >> 3) & 1) << 6);
            #pragma unroll
            for (int q = 0; q < 4; ++q) {
                f16x8 h;
                #pragma unroll
                for (int j = 0; j < 8; ++j) h[j] = (f16)vals[q * 8 + j];
                *reinterpret_cast<f16x8*>(crow + ((tg * 64 + q * 16) ^ swz)) = h;
            }
        } else if (t < 836) {                 // right pad zeros: tg in [805,840)
            int tg = t + 4;
            int swz = (((tg >> 1) & 3) << 4) | (((tg >> 3) & 1) << 6);
            f16x8 z;
            #pragma unroll
            for (int j = 0; j < 8; ++j) z[j] = (f16)0.f;
            #pragma unroll
            for (int q = 0; q < 4; ++q)
                *reinterpret_cast<f16x8*>(crow + ((tg * 64 + q * 16) ^ swz)) = z;
        }
    }
}

// ------------------------------------------------ one-shot MFMA conv v6 ----
// One tile per block, full-grid TLP; stage via global_load_lds (zero staging
// VGPRs); m204 bijective XCD swizzle with tb-fastest work order.
template<int KW, int STRIDE, int PW, int PAD_IN, int PAD_OUT, int NTB, int MINW, bool DO_LRELU>
__global__ __launch_bounds__(256, MINW) void conv_v6(
    const f16* __restrict__ inC, const f16* __restrict__ Ap,
    const float* __restrict__ bias, float* __restrict__ out,
    f16* __restrict__ outC, int Tout, int TpadIn, int TpadOut)
{
    constexpr int NT    = 64;
    constexpr int TR    = NT * STRIDE + KW - 1;
    constexpr int TRP   = (TR + 1) & ~1;
    constexpr int ROWB  = TRP * 64;
    constexpr int SLR   = TRP * 4;             // 16B slots per f-row
    constexpr int SL    = 6 * SLR;             // active slots
    constexpr int KPT   = (SL + 255) / 256;    // issue groups (unconditional)
    constexpr int TOFF  = (PAD_IN - PW) & 15;
    constexpr int NFOFF = 32 * STRIDE * 64;

    __shared__ char ldsb[KPT * 256 * 16];      // padded: slack absorbs tail group

    const int tid  = threadIdx.x;
    const int lane = tid & 63;
    const int wave = tid >> 6;

    // bijective XCD swizzle (m204), work order: tb fastest, then fblk, then b
    const int NWG = NTB * 129 * 4;
    int lin = blockIdx.x;
    int xcd = lin & 7, sl = lin >> 3;
    const int q = NWG / 8, r = NWG % 8;
    int work = (xcd < r ? xcd * (q + 1) : r * (q + 1) + (xcd - r) * q) + sl;
    const int tb   = work % NTB;
    int rem        = work / NTB;
    const int fblk = rem % 129;
    const int b    = rem / 129;
    const int f0   = fblk * 4;
    const int brow = b * FROWS + f0;           // copy row of fr=0 (fi=f0-1)
    const int t0   = tb * NT;
    const int base_t = t0 * STRIDE + (PAD_IN - PW);

    // ---- stage: branch-free global_load_lds, linear LDS dest
    {
        const char* inB = (const char*)inC;
        #pragma unroll
        for (int k = 0; k < KPT; ++k) {
            int s  = tid + k * 256;
            int fr = s / SLR;
            int s2 = s - fr * SLR;
            __builtin_amdgcn_global_load_lds(
                (const __attribute__((address_space(1))) void*)
                    (inB + ((size_t)(brow + fr) * TpadIn + base_t) * 64 + (size_t)s2 * 16),
                (__attribute__((address_space(3))) void*)
                    (ldsb + (k * 256 + (tid & 192)) * 16),
                16, 0, 0);
        }
    }

    // swizzled LDS read bases
    const int tln = lane & 31;
    const int hi  = lane >> 5;
    int baddr0[KW];
    #pragma unroll
    for (int kw = 0; kw < KW; ++kw) {
        int trow = tln * STRIDE + kw;
        int x = trow + TOFF;
        int swz = (((x >> 1) & 3) << 4) | (((x >> 3) & 1) << 6);
        baddr0[kw] = (trow * 64 + hi * 16) ^ swz;
    }

    float bs[16];
    #pragma unroll
    for (int rr = 0; rr < 16; ++rr) bs[rr] = bias[4 * hi + 8 * (rr >> 2) + (rr & 3)];

    __syncthreads();   // drains vmcnt(0): staged tile ready

    f32x16 acc[2];
    #pragma unroll
    for (int nf = 0; nf < 2; ++nf)
        #pragma unroll
        for (int rr = 0; rr < 16; ++rr) acc[nf][rr] = 0.f;

    const char* lrow = ldsb + wave * ROWB;
    #pragma unroll
    for (int df = 0; df < 3; ++df) {
        f16x8 a[KW * 2];
        #pragma unroll
        for (int kw = 0; kw < KW; ++kw)
            #pragma unroll
            for (int ch = 0; ch < 2; ++ch)
                a[kw * 2 + ch] = *reinterpret_cast<const f16x8*>(
                    Ap + (((df * KW + kw) * 2 + ch) << 9) + lane * 8);
        #pragma unroll
        for (int kw = 0; kw < KW; ++kw)
            #pragma unroll
            for (int ch = 0; ch < 2; ++ch)
                #pragma unroll
                for (int nf = 0; nf < 2; ++nf) {
                    f16x8 bf = *reinterpret_cast<const f16x8*>(
                        lrow + ((baddr0[kw] ^ (ch << 5)) + df * ROWB + nf * NFOFF));
                    acc[nf] = __builtin_amdgcn_mfma_f32_32x32x16_f16(a[kw * 2 + ch], bf, acc[nf], 0, 0, 0);
                }
    }

    // ---------------- epilogue ----------------
    const int f = f0 + wave;
    if (f >= NBINS) return;

    char* crow = nullptr;
    if constexpr (PAD_OUT > 0)
        crow = (char*)outC + ((size_t)(b * FROWS + f + 1)) * TpadOut * 64;

    #pragma unroll
    for (int nf = 0; nf < 2; ++nf) {
        int t = t0 + nf * 32 + tln;
        bool vt = (t < Tout);
        float vals[16];
        #pragma unroll
        for (int rr = 0; rr < 16; ++rr) {
            float v = acc[nf][rr] + bs[rr];
            if (DO_LRELU) v = (v > 0.f) ? v : 0.1f * v;
            vals[rr] = v;
        }
        if (vt) {
            #pragma unroll
            for (int rr = 0; rr < 16; ++rr) {
                int o = 4 * hi + 8 * (rr >> 2) + (rr & 3);
                out[(((size_t)b * 32 + o) * NBINS + f) * Tout + t] = vals[rr];
            }
        }
        if constexpr (PAD_OUT > 0) {
            int tg = t + PAD_OUT;
            int swz = (((tg >> 1) & 3) << 4) | (((tg >> 3) & 1) << 6);
            int rowbyte = (tg * 64) ^ swz;
            #pragma unroll
            for (int qq = 0; qq < 4; ++qq) {
                f16x4 hv;
                #pragma unroll
                for (int rr = 0; rr < 4; ++rr)
                    hv[rr] = vt ? (f16)vals[4 * qq + rr] : (f16)0.f;
                *reinterpret_cast<f16x4*>(crow + (rowbyte ^ ((4 * hi + 8 * qq) << 1))) = hv;
            }
        }
    }
    if constexpr (PAD_OUT > 0) {
        if (tb == 0 && lane < PAD_OUT * 4) {   // left pad zeros
            int tgp = lane >> 2, oct = lane & 3;
            f16x8 z;
            #pragma unroll
            for (int j = 0; j < 8; ++j) z[j] = (f16)0.f;
            *reinterpret_cast<f16x8*>(crow + tgp * 64 + oct * 16) = z;
        }
    }
}

// ------------------------------------------------------- final conv v2 ----
__global__ __launch_bounds__(256) void convo_v2(const f16* __restrict__ inC,
                                                const float* __restrict__ won,
                                                const float* __restrict__ bias,
                                                float* __restrict__ f5,
                                                float* __restrict__ flat)
{
    const int TP4 = 136;
    int blk = blockIdx.x;                  // (b, fpair)
    int b = blk / 257, fp = blk - (b * 257);
    int tid = threadIdx.x;
    int f = fp * 2 + (tid >> 7);
    int t = tid & 127;
    if (f >= NBINS || t >= 101) return;

    float acc = bias[0];
    #pragma unroll
    for (int df = 0; df < 3; ++df) {
        const char* row = (const char*)inC + ((size_t)(b * FROWS + f + df)) * TP4 * 64;
        #pragma unroll
        for (int kw = 0; kw < 3; ++kw) {
            int tg = t + kw;               // (t + kw - 1) + PAD_OUT(1)
            int swz = (((tg >> 1) & 3) << 4) | (((tg >> 3) & 1) << 6);
            #pragma unroll
            for (int q2 = 0; q2 < 4; ++q2) {
                f16x8 h = *reinterpret_cast<const f16x8*>(row + ((tg * 64 + q2 * 16) ^ swz));
                #pragma unroll
                for (int j = 0; j < 8; ++j)
                    acc = fmaf((float)h[j], won[((q2 * 8 + j) * 3 + df) * 3 + kw], acc);
            }
        }
    }
    size_t idx = ((size_t)(b * NBINS + f)) * 101 + t;
    f5[idx] = acc;
    flat[idx] = acc;
}

// ------------------------------------------------------------------ launch --
extern "C" void kernel_launch(void* const* d_in, const int* in_sizes, int n_in,
                              void* d_out, int out_size, void* d_ws, size_t ws_size,
                              hipStream_t stream)
{
    const float* y  = (const float*)d_in[0];
    const float* v0 = (const float*)d_in[1];
    const float* g0 = (const float*)d_in[2];
    const float* b0 = (const float*)d_in[3];
    const float* v1 = (const float*)d_in[4];
    const float* g1 = (const float*)d_in[5];
    const float* b1 = (const float*)d_in[6];
    const float* v2 = (const float*)d_in[7];
    const float* g2 = (const float*)d_in[8];
    const float* b2 = (const float*)d_in[9];
    const float* v3 = (const float*)d_in[10];
    const float* g3 = (const float*)d_in[11];
    const float* b3 = (const float*)d_in[12];
    const float* v4 = (const float*)d_in[13];
    const float* g4 = (const float*)d_in[14];
    const float* b4 = (const float*)d_in[15];
    const float* vo = (const float*)d_in[16];
    const float* go = (const float*)d_in[17];
    const float* bo = (const float*)d_in[18];

    float* out = (float*)d_out;
    float* ws  = (float*)d_ws;

    const size_t SFLAT = (size_t)4 * NBINS * 101;
    const size_t NF0   = (size_t)4 * 32 * NBINS * 801;
    const size_t NF1   = (size_t)4 * 32 * NBINS * 401;
    const size_t NF2   = (size_t)4 * 32 * NBINS * 201;
    const size_t NF3   = (size_t)4 * 32 * NBINS * 101;
    float* oflat = out;
    float* f0 = out + SFLAT;
    float* f1 = f0 + NF0;
    float* f2 = f1 + NF1;
    float* f3 = f2 + NF2;
    float* f4 = f3 + NF3;
    float* f5 = f4 + NF3;

    // mag (stride MAGT) stashed in the (not yet written) fmap1 region
    float* mag = f1;

    // ws layout: fp32 small weights, fp16 A-packs, fp16 activation copies
    const int TP0 = 840, TP1 = 456, TP2 = 264, TP3 = 136, TP4 = 136;
    size_t off = 0;
    float* w0n = ws + off; off += 1568;
    float* won = ws + off; off += 288;
    f16* A1 = (f16*)(ws + off);
    f16* A2 = A1 + 27648;
    f16* A3 = A2 + 27648;
    f16* A4 = A3 + 27648;               // 9216 elements
    f16* f0c = A4 + 9216;               // [4][515][840][32]
    f16* f1c = f0c + (size_t)4 * FROWS * TP0 * 32;   // [4][515][456][32]
    f16* f2c = f1c + (size_t)4 * FROWS * TP1 * 32;   // [4][515][264][32]
    f16* f3c = f2c + (size_t)4 * FROWS * TP2 * 32;   // [4][515][136][32]
    f16* f4c = f3c + (size_t)4 * FROWS * TP3 * 32;   // [4][515][136][32]

    prep_kernel<<<417, 256, 0, stream>>>(v0, g0, v1, g1, v2, g2, v3, g3,
                                         v4, g4, vo, go, w0n, won,
                                         A1, A2, A3, A4,
                                         f0c, f1c, f2c, f3c, f4c);

    stft_v2<<<dim3(101, 4), 256, 0, stream>>>(y, mag);

    double sh4 = -(1000.0 * log(0.001 * (5.0 / 7.0)) - 1000.0 * log(0.001)); // 336.472...
    double sh5 = -(1000.0 * log(0.001 * (6.0 / 7.0)) - 1000.0 * log(0.001)); // 154.150...
    float fr4 = (float)(sh4 - floor(sh4));
    float fr5 = (float)(sh5 - floor(sh5));

    harmonic_kernel<<<dim3(NBINS, 4), 256, 0, stream>>>(mag, w0n, b0, f0, f0c, fr4, fr5);

    // conv chain: one-shot gload_lds-staged, fp16-copy in, fp32 fmap out (+ copy)
    conv_v6<9, 2, 4, 4, 4, 7, 3, true><<<7 * 129 * 4, 256, 0, stream>>>(f0c, A1, b1, f1, f1c, 401, TP0, TP1);
    conv_v6<9, 2, 4, 4, 4, 4, 3, true><<<4 * 129 * 4, 256, 0, stream>>>(f1c, A2, b2, f2, f2c, 201, TP1, TP2);
    conv_v6<9, 2, 4, 4, 5, 2, 3, true><<<2 * 129 * 4, 256, 0, stream>>>(f2c, A3, b3, f3, f3c, 101, TP2, TP3);
    conv_v6<3, 1, 1, 5, 1, 2, 4, true><<<2 * 129 * 4, 256, 0, stream>>>(f3c, A4, b4, f4, f4c, 101, TP3, TP4);

    convo_v2<<<257 * 4, 256, 0, stream>>>(f4c, won, bo, f5, oflat);
}